// Round 1
// baseline (655.210 us; speedup 1.0000x reference)
//
#include <hip/hip_runtime.h>

typedef _Float16 f16;
typedef f16 f16x8 __attribute__((ext_vector_type(8)));
typedef float f32x4 __attribute__((ext_vector_type(4)));

// async global->LDS, 16B per lane; lds ptr must be wave-uniform base (HW adds lane*16)
__device__ __forceinline__ void gload16(const void* g, void* ldsbase) {
  __builtin_amdgcn_global_load_lds((const __attribute__((address_space(1))) unsigned int*)g,
                                   (__attribute__((address_space(3))) unsigned int*)ldsbase, 16, 0, 0);
}

// swizzled byte offset of 16B chunk c (k-chunk) of row `row` in a [rows][32] f16 tile
__device__ __forceinline__ int swz(int row, int c) {
  return row * 64 + ((c ^ ((row >> 1) & 3)) << 4);
}

// ---------------- generic NT GEMM: A [M x K] f16, B [N x K] f16 -> C f32 [M x N] (or Gram loss)
template<bool LOSS>
__global__ void __launch_bounds__(256)
gemm_nt_t(const f16* __restrict__ A, const f16* __restrict__ Bm, float* __restrict__ C,
          int K, int ldc, long sA, long sB, long sC, float scale, float* __restrict__ parts) {
  __shared__ f16 As[4096], Bs[4096];
  const int t = threadIdx.x, l = t & 63, w = t >> 6, wr = w >> 1, wc = w & 1;
  const long b = blockIdx.z;
  const f16* Ab = A + b * sA + (long)(blockIdx.y * 128) * K;
  const f16* Bb = Bm + b * sB + (long)(blockIdx.x * 128) * K;
  const int r0 = t >> 2, cs = (t & 3) ^ ((r0 >> 1) & 3);
  const f16* aS0 = Ab + (long)r0 * K + cs * 8;
  const f16* aS1 = Ab + (long)(r0 + 64) * K + cs * 8;
  const f16* bS0 = Bb + (long)r0 * K + cs * 8;
  const f16* bS1 = Bb + (long)(r0 + 64) * K + cs * 8;
  int offA[4], offB[4];
#pragma unroll
  for (int i = 0; i < 4; ++i) {
    int ra = wr * 64 + i * 16 + (l & 15);
    offA[i] = swz(ra, l >> 4);
    int rb = wc * 64 + i * 16 + (l & 15);
    offB[i] = swz(rb, l >> 4);
  }
  f32x4 acc[4][4] = {};
  for (int k0 = 0; k0 < K; k0 += 32) {
    gload16(aS0 + k0, As + w * 512);
    gload16(aS1 + k0, As + 2048 + w * 512);
    gload16(bS0 + k0, Bs + w * 512);
    gload16(bS1 + k0, Bs + 2048 + w * 512);
    __syncthreads();
    f16x8 af[4], bf[4];
#pragma unroll
    for (int i = 0; i < 4; ++i) {
      af[i] = *(const f16x8*)((const char*)As + offA[i]);
      bf[i] = *(const f16x8*)((const char*)Bs + offB[i]);
    }
#pragma unroll
    for (int mi = 0; mi < 4; ++mi)
#pragma unroll
      for (int ni = 0; ni < 4; ++ni)
        acc[mi][ni] = __builtin_amdgcn_mfma_f32_16x16x32_f16(af[mi], bf[ni], acc[mi][ni], 0, 0, 0);
    __syncthreads();
  }
  if (!LOSS) {
    float* Cb = C + b * sC + (long)(blockIdx.y * 128 + wr * 64) * ldc + blockIdx.x * 128 + wc * 64;
#pragma unroll
    for (int mi = 0; mi < 4; ++mi)
#pragma unroll
      for (int ni = 0; ni < 4; ++ni)
#pragma unroll
        for (int q = 0; q < 4; ++q)
          Cb[(long)(mi * 16 + (l >> 4) * 4 + q) * ldc + ni * 16 + (l & 15)] = acc[mi][ni][q] * scale;
  } else {
    const int gr0 = blockIdx.y * 128 + wr * 64 + (l >> 4) * 4;
    const int gc0 = blockIdx.x * 128 + wc * 64 + (l & 15);
    float p = 0.f;
#pragma unroll
    for (int mi = 0; mi < 4; ++mi)
#pragma unroll
      for (int ni = 0; ni < 4; ++ni)
#pragma unroll
        for (int q = 0; q < 4; ++q) {
          float e = acc[mi][ni][q];
          if (gr0 + mi * 16 + q == gc0 + ni * 16) e -= 1.f;
          p += e * e;
        }
#pragma unroll
    for (int d = 32; d; d >>= 1) p += __shfl_down(p, d);
    __shared__ float red[4];
    if (l == 0) red[w] = p;
    __syncthreads();
    if (t == 0) parts[blockIdx.x + blockIdx.y * 8 + blockIdx.z * 64] = red[0] + red[1] + red[2] + red[3];
  }
}

// ---------------- projection, output natural [C x P]: Q[o,p] = sum_i W[o,i] X[i,p] + b[o]
__global__ void __launch_bounds__(256)
proj_q(const float* __restrict__ X, const f16* __restrict__ W16, const float* __restrict__ bias,
       f16* __restrict__ Q, int P) {
  __shared__ f16 As[4096], Bs[4096];  // As = W [o][i], Bs = Xt [p][i]
  const int t = threadIdx.x, l = t & 63, w = t >> 6, wr = w >> 1, wc = w & 1;
  const int bg = blockIdx.z, g = bg & 3;
  const long b = bg >> 2;
  const int p0 = blockIdx.x * 128, m0 = blockIdx.y * 128;
  const float* Xb = X + b * 1024 * P + (long)g * 256 * P;
  const f16* Wg = W16 + g * 65536 + m0 * 256;
  const int r0 = t >> 2, cs = (t & 3) ^ ((r0 >> 1) & 3);
  const f16* wS0 = Wg + r0 * 256 + cs * 8;
  const f16* wS1 = Wg + (r0 + 64) * 256 + cs * 8;
  const int xp = t & 63, xc = t >> 6;
  const float* xS = Xb + (long)(xc * 8) * P + p0 + xp;
  const int xo0 = swz(xp, xc), xo1 = swz(xp + 64, xc);
  int offA[4], offB[4];
#pragma unroll
  for (int i = 0; i < 4; ++i) {
    int ra = wr * 64 + i * 16 + (l & 15);
    offA[i] = swz(ra, l >> 4);
    int rb = wc * 64 + i * 16 + (l & 15);
    offB[i] = swz(rb, l >> 4);
  }
  f32x4 acc[4][4] = {};
  for (int k0 = 0; k0 < 256; k0 += 32) {
    gload16(wS0 + k0, As + w * 512);
    gload16(wS1 + k0, As + 2048 + w * 512);
    const float* xs = xS + (long)k0 * P;
    f16x8 v0, v1;
#pragma unroll
    for (int d = 0; d < 8; ++d) v0[d] = (f16)xs[(long)d * P];
#pragma unroll
    for (int d = 0; d < 8; ++d) v1[d] = (f16)xs[(long)d * P + 64];
    *(f16x8*)((char*)Bs + xo0) = v0;
    *(f16x8*)((char*)Bs + xo1) = v1;
    __syncthreads();
    f16x8 af[4], bf[4];
#pragma unroll
    for (int i = 0; i < 4; ++i) {
      af[i] = *(const f16x8*)((const char*)As + offA[i]);
      bf[i] = *(const f16x8*)((const char*)Bs + offB[i]);
    }
#pragma unroll
    for (int mi = 0; mi < 4; ++mi)
#pragma unroll
      for (int ni = 0; ni < 4; ++ni)
        acc[mi][ni] = __builtin_amdgcn_mfma_f32_16x16x32_f16(af[mi], bf[ni], acc[mi][ni], 0, 0, 0);
    __syncthreads();
  }
  f16* Qb = Q + b * 1048576 + (long)(g * 256 + m0 + wr * 64) * 1024 + p0 + wc * 64;
#pragma unroll
  for (int mi = 0; mi < 4; ++mi)
#pragma unroll
    for (int q = 0; q < 4; ++q) {
      float bv = bias[g * 256 + m0 + wr * 64 + mi * 16 + (l >> 4) * 4 + q];
#pragma unroll
      for (int ni = 0; ni < 4; ++ni)
        Qb[(long)(mi * 16 + (l >> 4) * 4 + q) * 1024 + ni * 16 + (l & 15)] = (f16)(acc[mi][ni][q] + bv);
    }
}

// ---------------- projection, output transposed [P x C]: Yt[p,c] = sum_i X[i,p] W[o,i] + b[c]
__global__ void __launch_bounds__(256)
proj_kv(const float* __restrict__ X, const f16* __restrict__ W16, const float* __restrict__ bias,
        f16* __restrict__ Yt, int P) {
  __shared__ f16 As[4096], Bs[4096];  // As = Xt [p][i], Bs = W [o][i]
  const int t = threadIdx.x, l = t & 63, w = t >> 6, wr = w >> 1, wc = w & 1;
  const int bg = blockIdx.z, g = bg & 3;
  const long b = bg >> 2;
  const int p0 = blockIdx.y * 128, n0 = blockIdx.x * 128;
  const float* Xb = X + b * 1024 * P + (long)g * 256 * P;
  const f16* Wg = W16 + g * 65536 + n0 * 256;
  const int r0 = t >> 2, cs = (t & 3) ^ ((r0 >> 1) & 3);
  const f16* wS0 = Wg + r0 * 256 + cs * 8;
  const f16* wS1 = Wg + (r0 + 64) * 256 + cs * 8;
  const int xp = t & 63, xc = t >> 6;
  const float* xS = Xb + (long)(xc * 8) * P + p0 + xp;
  const int xo0 = swz(xp, xc), xo1 = swz(xp + 64, xc);
  int offA[4], offB[4];
#pragma unroll
  for (int i = 0; i < 4; ++i) {
    int ra = wr * 64 + i * 16 + (l & 15);
    offA[i] = swz(ra, l >> 4);
    int rb = wc * 64 + i * 16 + (l & 15);
    offB[i] = swz(rb, l >> 4);
  }
  f32x4 acc[4][4] = {};
  for (int k0 = 0; k0 < 256; k0 += 32) {
    gload16(wS0 + k0, Bs + w * 512);
    gload16(wS1 + k0, Bs + 2048 + w * 512);
    const float* xs = xS + (long)k0 * P;
    f16x8 v0, v1;
#pragma unroll
    for (int d = 0; d < 8; ++d) v0[d] = (f16)xs[(long)d * P];
#pragma unroll
    for (int d = 0; d < 8; ++d) v1[d] = (f16)xs[(long)d * P + 64];
    *(f16x8*)((char*)As + xo0) = v0;
    *(f16x8*)((char*)As + xo1) = v1;
    __syncthreads();
    f16x8 af[4], bf[4];
#pragma unroll
    for (int i = 0; i < 4; ++i) {
      af[i] = *(const f16x8*)((const char*)As + offA[i]);
      bf[i] = *(const f16x8*)((const char*)Bs + offB[i]);
    }
#pragma unroll
    for (int mi = 0; mi < 4; ++mi)
#pragma unroll
      for (int ni = 0; ni < 4; ++ni)
        acc[mi][ni] = __builtin_amdgcn_mfma_f32_16x16x32_f16(af[mi], bf[ni], acc[mi][ni], 0, 0, 0);
    __syncthreads();
  }
  f16* Yb = Yt + b * P * 1024 + (long)(p0 + wr * 64) * 1024 + g * 256 + n0 + wc * 64;
  float bcol[4];
#pragma unroll
  for (int ni = 0; ni < 4; ++ni) bcol[ni] = bias[g * 256 + n0 + wc * 64 + ni * 16 + (l & 15)];
#pragma unroll
  for (int mi = 0; mi < 4; ++mi)
#pragma unroll
    for (int q = 0; q < 4; ++q)
#pragma unroll
      for (int ni = 0; ni < 4; ++ni)
        Yb[(long)(mi * 16 + (l >> 4) * 4 + q) * 1024 + ni * 16 + (l & 15)] = (f16)(acc[mi][ni][q] + bcol[ni]);
}

// ---------------- column softmax over Pk, in-place f32, plus f16 H and f16 H^T
__global__ void __launch_bounds__(256)
softmax_k(float* __restrict__ S, f16* __restrict__ H16, f16* __restrict__ H16t) {
  const int t = threadIdx.x, tj = t & 63, ti = t >> 6;
  const long b = blockIdx.y;
  const int j0 = blockIdx.x * 64;
  float* Sb = S + b * 4194304;
  float m = -1e30f, lsum = 0.f;
  {
    const float* p = Sb + j0 + tj;
    for (int i = ti; i < 1024; i += 4) {
      float s = p[(long)i * 4096];
      float mn = fmaxf(m, s);
      lsum = lsum * __expf(m - mn) + __expf(s - mn);
      m = mn;
    }
  }
  __shared__ float ms[4][64], ls[4][64], mf[64], lf[64];
  ms[ti][tj] = m; ls[ti][tj] = lsum;
  __syncthreads();
  if (t < 64) {
    float M = fmaxf(fmaxf(ms[0][t], ms[1][t]), fmaxf(ms[2][t], ms[3][t]));
    float L = 0.f;
#pragma unroll
    for (int r = 0; r < 4; ++r) L += ls[r][t] * __expf(ms[r][t] - M);
    mf[t] = M; lf[t] = 1.f / L;
  }
  __syncthreads();
  const float M = mf[tj], Li = lf[tj];
  __shared__ float T[64][65];
  f16* Hb = H16 + b * 4194304;
  f16* Htb = H16t + b * 4194304;
  for (int ic = 0; ic < 1024; ic += 64) {
#pragma unroll
    for (int k = 0; k < 16; ++k) {
      int i = ic + ti + k * 4;
      long idx = (long)i * 4096 + j0 + tj;
      float h = __expf(Sb[idx] - M) * Li;
      Sb[idx] = h;
      Hb[idx] = (f16)h;
      T[ti + k * 4][tj] = h;
    }
    __syncthreads();
    const int jj = t >> 3, q8 = t & 7;
#pragma unroll
    for (int r2 = 0; r2 < 2; ++r2) {
      int j = jj + r2 * 32;
      f16x8 v;
#pragma unroll
      for (int s2 = 0; s2 < 8; ++s2) v[s2] = (f16)T[q8 * 8 + s2][j];
      *(f16x8*)(Htb + (long)(j0 + j) * 1024 + ic + q8 * 8) = v;
    }
    __syncthreads();
  }
}

__global__ void cvt_f16(const float* __restrict__ s, f16* __restrict__ d, int n) {
  int i = blockIdx.x * 256 + threadIdx.x;
  if (i < n) d[i] = (f16)s[i];
}

__global__ void __launch_bounds__(256)
finalize_k(const float* __restrict__ parts, float* __restrict__ o) {
  const int t = threadIdx.x;
  float s = parts[t] + parts[t + 256];
#pragma unroll
  for (int d = 32; d; d >>= 1) s += __shfl_down(s, d);
  __shared__ float red[4];
  if ((t & 63) == 0) red[t >> 6] = s;
  __syncthreads();
  if (t == 0) *o = (red[0] + red[1] + red[2] + red[3]) * (1.0f / 8388608.0f);
}

extern "C" void kernel_launch(void* const* d_in, const int* in_sizes, int n_in,
                              void* d_out, int out_size, void* d_ws, size_t ws_size,
                              hipStream_t stream) {
  const float* Xq = (const float*)d_in[0];
  const float* Xk = (const float*)d_in[1];
  const float* Wq = (const float*)d_in[2];
  const float* bq = (const float*)d_in[3];
  const float* Wk = (const float*)d_in[4];
  const float* bk = (const float*)d_in[5];
  const float* Wv = (const float*)d_in[6];
  const float* bv = (const float*)d_in[7];
  float* out = (float*)d_out;
  float* loss_out = out + 33554432;
  float* Hout = out + 33554433;  // [8][1024][4096], used first as S scratch then H f32

  char* ws = (char*)d_ws;
  f16* W16q = (f16*)(ws);
  f16* W16k = (f16*)(ws + (1 << 19));
  f16* W16v = (f16*)(ws + 2L * (1 << 19));
  f16* Q16  = (f16*)(ws + 3L * (1 << 19));                                  // [8][1024][1024]
  f16* Kt16 = (f16*)(ws + 3L * (1 << 19) + (1L << 24));                     // [8][1024][1024]
  f16* Vt16 = (f16*)(ws + 3L * (1 << 19) + 2L * (1 << 24));                 // [8][4096][1024]
  f16* H16  = (f16*)(ws + 3L * (1 << 19) + 2L * (1 << 24) + (1L << 26));    // [8][1024][4096]
  f16* H16t = (f16*)(ws + 3L * (1 << 19) + 2L * (1 << 24) + 2L * (1 << 26));// [8][4096][1024]
  float* parts = (float*)(ws + 3L * (1 << 19) + 2L * (1 << 24) + 3L * (1 << 26)); // 512 f32

  cvt_f16<<<1024, 256, 0, stream>>>(Wq, W16q, 262144);
  cvt_f16<<<1024, 256, 0, stream>>>(Wk, W16k, 262144);
  cvt_f16<<<1024, 256, 0, stream>>>(Wv, W16v, 262144);

  // Q [C x Pk] natural; K,V transposed [P x C]
  proj_q <<<dim3(8, 2, 32), 256, 0, stream>>>(Xk, W16q, bq, Q16, 1024);
  proj_kv<<<dim3(2, 8, 32), 256, 0, stream>>>(Xk, W16k, bk, Kt16, 1024);
  proj_kv<<<dim3(2, 32, 32), 256, 0, stream>>>(Xq, W16v, bv, Vt16, 4096);

  // S = K^T V * (1/32)  -> Hout region (f32)
  gemm_nt_t<false><<<dim3(32, 8, 8), 256, 0, stream>>>(Kt16, Vt16, Hout, 1024, 4096,
      1048576L, 4194304L, 4194304L, 0.03125f, nullptr);

  // softmax over Pk (in-place), emit H16 and H16^T
  softmax_k<<<dim3(64, 8), 256, 0, stream>>>(Hout, H16, H16t);

  // out = Q * H   (A = Q [C x Pk], B = H^T [Pq x Pk])
  gemm_nt_t<false><<<dim3(32, 8, 8), 256, 0, stream>>>(Q16, H16t, out, 1024, 4096,
      1048576L, 4194304L, 4194304L, 1.0f, nullptr);

  // sparse loss: mean((H H^T - I)^2)
  gemm_nt_t<true><<<dim3(8, 8, 8), 256, 0, stream>>>(H16, H16, nullptr, 4096, 0,
      4194304L, 4194304L, 0L, 1.0f, parts);
  finalize_k<<<1, 256, 0, stream>>>(parts, loss_out);
}

// Round 2
// 554.912 us; speedup vs baseline: 1.1807x; 1.1807x over previous
//
#include <hip/hip_runtime.h>

typedef _Float16 f16;
typedef f16 f16x8 __attribute__((ext_vector_type(8)));
typedef float f32x4 __attribute__((ext_vector_type(4)));

// async global->LDS, 16B per lane; lds ptr must be wave-uniform base (HW adds lane*16)
__device__ __forceinline__ void gload16(const void* g, void* ldsbase) {
  __builtin_amdgcn_global_load_lds((const __attribute__((address_space(1))) unsigned int*)g,
                                   (__attribute__((address_space(3))) unsigned int*)ldsbase, 16, 0, 0);
}

// swizzled byte offset of 16B chunk c (k-chunk) of row `row` in a [rows][32] f16 tile
__device__ __forceinline__ int swz(int row, int c) {
  return row * 64 + ((c ^ ((row >> 1) & 3)) << 4);
}

// ---------------- generic NT GEMM: A [M x K] f16, B [N x K] f16
// MODE 0: C = A*B^T * scale (f32)
// MODE 1: Gram loss partials, triangle-only (A==B), identity subtracted
// MODE 2: C = exp(A*B^T * scale), plus per-column (N) partial sums -> parts[(b*8+by)*4096 + j]
template<int MODE>
__global__ void __launch_bounds__(256)
gemm_nt_t(const f16* __restrict__ A, const f16* __restrict__ Bm, float* __restrict__ C,
          int K, int ldc, long sA, long sB, long sC, float scale, float* __restrict__ parts) {
  const int t = threadIdx.x, l = t & 63, w = t >> 6, wr = w >> 1, wc = w & 1;
  if (MODE == 1 && blockIdx.x < blockIdx.y) {  // symmetric Gram: skip lower triangle
    if (t == 0) parts[blockIdx.x + blockIdx.y * 8 + blockIdx.z * 64] = 0.f;
    return;
  }
  __shared__ f16 As[4096], Bs[4096];
  const long b = blockIdx.z;
  const f16* Ab = A + b * sA + (long)(blockIdx.y * 128) * K;
  const f16* Bb = Bm + b * sB + (long)(blockIdx.x * 128) * K;
  const int r0 = t >> 2, cs = (t & 3) ^ ((r0 >> 1) & 3);
  const f16* aS0 = Ab + (long)r0 * K + cs * 8;
  const f16* aS1 = Ab + (long)(r0 + 64) * K + cs * 8;
  const f16* bS0 = Bb + (long)r0 * K + cs * 8;
  const f16* bS1 = Bb + (long)(r0 + 64) * K + cs * 8;
  int offA[4], offB[4];
#pragma unroll
  for (int i = 0; i < 4; ++i) {
    int ra = wr * 64 + i * 16 + (l & 15);
    offA[i] = swz(ra, l >> 4);
    int rb = wc * 64 + i * 16 + (l & 15);
    offB[i] = swz(rb, l >> 4);
  }
  f32x4 acc[4][4] = {};
  for (int k0 = 0; k0 < K; k0 += 32) {
    gload16(aS0 + k0, As + w * 512);
    gload16(aS1 + k0, As + 2048 + w * 512);
    gload16(bS0 + k0, Bs + w * 512);
    gload16(bS1 + k0, Bs + 2048 + w * 512);
    __syncthreads();
    f16x8 af[4], bf[4];
#pragma unroll
    for (int i = 0; i < 4; ++i) {
      af[i] = *(const f16x8*)((const char*)As + offA[i]);
      bf[i] = *(const f16x8*)((const char*)Bs + offB[i]);
    }
#pragma unroll
    for (int mi = 0; mi < 4; ++mi)
#pragma unroll
      for (int ni = 0; ni < 4; ++ni)
        acc[mi][ni] = __builtin_amdgcn_mfma_f32_16x16x32_f16(af[mi], bf[ni], acc[mi][ni], 0, 0, 0);
    __syncthreads();
  }
  if (MODE == 0) {
    float* Cb = C + b * sC + (long)(blockIdx.y * 128 + wr * 64) * ldc + blockIdx.x * 128 + wc * 64;
#pragma unroll
    for (int mi = 0; mi < 4; ++mi)
#pragma unroll
      for (int ni = 0; ni < 4; ++ni)
#pragma unroll
        for (int q = 0; q < 4; ++q)
          Cb[(long)(mi * 16 + (l >> 4) * 4 + q) * ldc + ni * 16 + (l & 15)] = acc[mi][ni][q] * scale;
  } else if (MODE == 2) {
    float* Cb = C + b * sC + (long)(blockIdx.y * 128 + wr * 64) * ldc + blockIdx.x * 128 + wc * 64;
    float csum[4] = {};
#pragma unroll
    for (int mi = 0; mi < 4; ++mi)
#pragma unroll
      for (int ni = 0; ni < 4; ++ni)
#pragma unroll
        for (int q = 0; q < 4; ++q) {
          float e = __expf(acc[mi][ni][q] * scale);
          Cb[(long)(mi * 16 + (l >> 4) * 4 + q) * ldc + ni * 16 + (l & 15)] = e;
          csum[ni] += e;
        }
    // combine the 4 row-groups (l>>4) holding the same column
#pragma unroll
    for (int ni = 0; ni < 4; ++ni) {
      csum[ni] += __shfl_xor(csum[ni], 16);
      csum[ni] += __shfl_xor(csum[ni], 32);
    }
    __shared__ float colp[2][128];
    if (l < 16) {
#pragma unroll
      for (int ni = 0; ni < 4; ++ni) colp[wr][wc * 64 + ni * 16 + l] = csum[ni];
    }
    __syncthreads();
    if (t < 128) {
      float s2 = colp[0][t] + colp[1][t];
      parts[(b * 8 + blockIdx.y) * 4096 + blockIdx.x * 128 + t] = s2;
    }
  } else {  // MODE 1: Gram loss
    const float wgt = (blockIdx.x == blockIdx.y) ? 1.f : 2.f;
    const int gr0 = blockIdx.y * 128 + wr * 64 + (l >> 4) * 4;
    const int gc0 = blockIdx.x * 128 + wc * 64 + (l & 15);
    float p = 0.f;
#pragma unroll
    for (int mi = 0; mi < 4; ++mi)
#pragma unroll
      for (int ni = 0; ni < 4; ++ni)
#pragma unroll
        for (int q = 0; q < 4; ++q) {
          float e = acc[mi][ni][q];
          if (gr0 + mi * 16 + q == gc0 + ni * 16) e -= 1.f;
          p += e * e;
        }
    p *= wgt;
#pragma unroll
    for (int d = 32; d; d >>= 1) p += __shfl_down(p, d);
    __shared__ float red[4];
    if (l == 0) red[w] = p;
    __syncthreads();
    if (t == 0) parts[blockIdx.x + blockIdx.y * 8 + blockIdx.z * 64] = red[0] + red[1] + red[2] + red[3];
  }
}

// ---------------- projection, output natural [C x P]: Q[o,p] = sum_i W[o,i] X[i,p] + b[o]
__global__ void __launch_bounds__(256)
proj_q(const float* __restrict__ X, const f16* __restrict__ W16, const float* __restrict__ bias,
       f16* __restrict__ Q, int P) {
  __shared__ f16 As[4096], Bs[4096];  // As = W [o][i], Bs = Xt [p][i]
  const int t = threadIdx.x, l = t & 63, w = t >> 6, wr = w >> 1, wc = w & 1;
  const int bg = blockIdx.z, g = bg & 3;
  const long b = bg >> 2;
  const int p0 = blockIdx.x * 128, m0 = blockIdx.y * 128;
  const float* Xb = X + b * 1024 * P + (long)g * 256 * P;
  const f16* Wg = W16 + g * 65536 + m0 * 256;
  const int r0 = t >> 2, cs = (t & 3) ^ ((r0 >> 1) & 3);
  const f16* wS0 = Wg + r0 * 256 + cs * 8;
  const f16* wS1 = Wg + (r0 + 64) * 256 + cs * 8;
  const int xp = t & 63, xc = t >> 6;
  const float* xS = Xb + (long)(xc * 8) * P + p0 + xp;
  const int xo0 = swz(xp, xc), xo1 = swz(xp + 64, xc);
  int offA[4], offB[4];
#pragma unroll
  for (int i = 0; i < 4; ++i) {
    int ra = wr * 64 + i * 16 + (l & 15);
    offA[i] = swz(ra, l >> 4);
    int rb = wc * 64 + i * 16 + (l & 15);
    offB[i] = swz(rb, l >> 4);
  }
  f32x4 acc[4][4] = {};
  for (int k0 = 0; k0 < 256; k0 += 32) {
    gload16(wS0 + k0, As + w * 512);
    gload16(wS1 + k0, As + 2048 + w * 512);
    const float* xs = xS + (long)k0 * P;
    f16x8 v0, v1;
#pragma unroll
    for (int d = 0; d < 8; ++d) v0[d] = (f16)xs[(long)d * P];
#pragma unroll
    for (int d = 0; d < 8; ++d) v1[d] = (f16)xs[(long)d * P + 64];
    *(f16x8*)((char*)Bs + xo0) = v0;
    *(f16x8*)((char*)Bs + xo1) = v1;
    __syncthreads();
    f16x8 af[4], bf[4];
#pragma unroll
    for (int i = 0; i < 4; ++i) {
      af[i] = *(const f16x8*)((const char*)As + offA[i]);
      bf[i] = *(const f16x8*)((const char*)Bs + offB[i]);
    }
#pragma unroll
    for (int mi = 0; mi < 4; ++mi)
#pragma unroll
      for (int ni = 0; ni < 4; ++ni)
        acc[mi][ni] = __builtin_amdgcn_mfma_f32_16x16x32_f16(af[mi], bf[ni], acc[mi][ni], 0, 0, 0);
    __syncthreads();
  }
  f16* Qb = Q + b * 1048576 + (long)(g * 256 + m0 + wr * 64) * 1024 + p0 + wc * 64;
#pragma unroll
  for (int mi = 0; mi < 4; ++mi)
#pragma unroll
    for (int q = 0; q < 4; ++q) {
      float bv = bias[g * 256 + m0 + wr * 64 + mi * 16 + (l >> 4) * 4 + q];
#pragma unroll
      for (int ni = 0; ni < 4; ++ni)
        Qb[(long)(mi * 16 + (l >> 4) * 4 + q) * 1024 + ni * 16 + (l & 15)] = (f16)(acc[mi][ni][q] + bv);
    }
}

// ---------------- projection, output transposed [P x C]: Yt[p,c] = sum_i X[i,p] W[o,i] + b[c]
__global__ void __launch_bounds__(256)
proj_kv(const float* __restrict__ X, const f16* __restrict__ W16, const float* __restrict__ bias,
        f16* __restrict__ Yt, int P) {
  __shared__ f16 As[4096], Bs[4096];  // As = Xt [p][i], Bs = W [o][i]
  const int t = threadIdx.x, l = t & 63, w = t >> 6, wr = w >> 1, wc = w & 1;
  const int bg = blockIdx.z, g = bg & 3;
  const long b = bg >> 2;
  const int p0 = blockIdx.y * 128, n0 = blockIdx.x * 128;
  const float* Xb = X + b * 1024 * P + (long)g * 256 * P;
  const f16* Wg = W16 + g * 65536 + n0 * 256;
  const int r0 = t >> 2, cs = (t & 3) ^ ((r0 >> 1) & 3);
  const f16* wS0 = Wg + r0 * 256 + cs * 8;
  const f16* wS1 = Wg + (r0 + 64) * 256 + cs * 8;
  const int xp = t & 63, xc = t >> 6;
  const float* xS = Xb + (long)(xc * 8) * P + p0 + xp;
  const int xo0 = swz(xp, xc), xo1 = swz(xp + 64, xc);
  int offA[4], offB[4];
#pragma unroll
  for (int i = 0; i < 4; ++i) {
    int ra = wr * 64 + i * 16 + (l & 15);
    offA[i] = swz(ra, l >> 4);
    int rb = wc * 64 + i * 16 + (l & 15);
    offB[i] = swz(rb, l >> 4);
  }
  f32x4 acc[4][4] = {};
  for (int k0 = 0; k0 < 256; k0 += 32) {
    gload16(wS0 + k0, Bs + w * 512);
    gload16(wS1 + k0, Bs + 2048 + w * 512);
    const float* xs = xS + (long)k0 * P;
    f16x8 v0, v1;
#pragma unroll
    for (int d = 0; d < 8; ++d) v0[d] = (f16)xs[(long)d * P];
#pragma unroll
    for (int d = 0; d < 8; ++d) v1[d] = (f16)xs[(long)d * P + 64];
    *(f16x8*)((char*)As + xo0) = v0;
    *(f16x8*)((char*)As + xo1) = v1;
    __syncthreads();
    f16x8 af[4], bf[4];
#pragma unroll
    for (int i = 0; i < 4; ++i) {
      af[i] = *(const f16x8*)((const char*)As + offA[i]);
      bf[i] = *(const f16x8*)((const char*)Bs + offB[i]);
    }
#pragma unroll
    for (int mi = 0; mi < 4; ++mi)
#pragma unroll
      for (int ni = 0; ni < 4; ++ni)
        acc[mi][ni] = __builtin_amdgcn_mfma_f32_16x16x32_f16(af[mi], bf[ni], acc[mi][ni], 0, 0, 0);
    __syncthreads();
  }
  f16* Yb = Yt + b * P * 1024 + (long)(p0 + wr * 64) * 1024 + g * 256 + n0 + wc * 64;
  float bcol[4];
#pragma unroll
  for (int ni = 0; ni < 4; ++ni) bcol[ni] = bias[g * 256 + n0 + wc * 64 + ni * 16 + (l & 15)];
#pragma unroll
  for (int mi = 0; mi < 4; ++mi)
#pragma unroll
    for (int q = 0; q < 4; ++q)
#pragma unroll
      for (int ni = 0; ni < 4; ++ni)
        Yb[(long)(mi * 16 + (l >> 4) * 4 + q) * 1024 + ni * 16 + (l & 15)] = (f16)(acc[mi][ni][q] + bcol[ni]);
}

// ---------------- finalize softmax: H = expS/L (in place), emit H16 and H16^T
// grid: (Pq/64, Pk/64, B), 256 threads
__global__ void __launch_bounds__(256)
h_finalize(float* __restrict__ Hf, const float* __restrict__ colsum,
           f16* __restrict__ H16, f16* __restrict__ H16t) {
  const int t = threadIdx.x, tj = t & 63, ti = t >> 6;
  const long b = blockIdx.z;
  const int j0 = blockIdx.x * 64, i0 = blockIdx.y * 64;
  __shared__ float inv_s[64];
  __shared__ float T[64][65];
  if (t < 64) {
    const float* cp = colsum + b * 8 * 4096 + j0 + t;
    float s = 0.f;
#pragma unroll
    for (int my = 0; my < 8; ++my) s += cp[my * 4096];
    inv_s[t] = 1.f / s;
  }
  __syncthreads();
  float* Hb = Hf + b * 4194304;
  f16* H16b = H16 + b * 4194304;
  const float inv = inv_s[tj];
#pragma unroll
  for (int it = 0; it < 16; ++it) {
    int i = i0 + ti + it * 4;
    long idx = (long)i * 4096 + j0 + tj;
    float h = Hb[idx] * inv;
    Hb[idx] = h;
    H16b[idx] = (f16)h;
    T[tj][ti + it * 4] = h;
  }
  __syncthreads();
  const int j = t >> 2, q = t & 3;
  f16* dst = H16t + b * 4194304 + (long)(j0 + j) * 1024 + i0 + q * 16;
  f16x8 v0, v1;
#pragma unroll
  for (int s2 = 0; s2 < 8; ++s2) v0[s2] = (f16)T[j][q * 16 + s2];
#pragma unroll
  for (int s2 = 0; s2 < 8; ++s2) v1[s2] = (f16)T[j][q * 16 + 8 + s2];
  *(f16x8*)dst = v0;
  *(f16x8*)(dst + 8) = v1;
}

__global__ void cvt_f16(const float* __restrict__ s, f16* __restrict__ d, int n) {
  int i = blockIdx.x * 256 + threadIdx.x;
  if (i < n) d[i] = (f16)s[i];
}

__global__ void __launch_bounds__(256)
finalize_k(const float* __restrict__ parts, float* __restrict__ o) {
  const int t = threadIdx.x;
  float s = parts[t] + parts[t + 256];
#pragma unroll
  for (int d = 32; d; d >>= 1) s += __shfl_down(s, d);
  __shared__ float red[4];
  if ((t & 63) == 0) red[t >> 6] = s;
  __syncthreads();
  if (t == 0) *o = (red[0] + red[1] + red[2] + red[3]) * (1.0f / 8388608.0f);
}

extern "C" void kernel_launch(void* const* d_in, const int* in_sizes, int n_in,
                              void* d_out, int out_size, void* d_ws, size_t ws_size,
                              hipStream_t stream) {
  const float* Xq = (const float*)d_in[0];
  const float* Xk = (const float*)d_in[1];
  const float* Wq = (const float*)d_in[2];
  const float* bq = (const float*)d_in[3];
  const float* Wk = (const float*)d_in[4];
  const float* bk = (const float*)d_in[5];
  const float* Wv = (const float*)d_in[6];
  const float* bv = (const float*)d_in[7];
  float* out = (float*)d_out;
  float* loss_out = out + 33554432;
  float* Hout = out + 33554433;  // [8][1024][4096]: first exp(S), then H f32

  char* ws = (char*)d_ws;
  f16* W16q = (f16*)(ws);
  f16* W16k = (f16*)(ws + (1 << 19));
  f16* W16v = (f16*)(ws + 2L * (1 << 19));
  f16* Q16  = (f16*)(ws + 3L * (1 << 19));                                  // [8][1024][1024]
  f16* Kt16 = (f16*)(ws + 3L * (1 << 19) + (1L << 24));                     // [8][1024][1024]
  f16* Vt16 = (f16*)(ws + 3L * (1 << 19) + 2L * (1 << 24));                 // [8][4096][1024]
  f16* H16  = (f16*)(ws + 3L * (1 << 19) + 2L * (1 << 24) + (1L << 26));    // [8][1024][4096]
  f16* H16t = (f16*)(ws + 3L * (1 << 19) + 2L * (1 << 24) + 2L * (1 << 26));// [8][4096][1024]
  float* parts = (float*)(ws + 3L * (1 << 19) + 2L * (1 << 24) + 3L * (1 << 26)); // 512 f32
  // colsum [8][8][4096] f32 = 1 MB, overlaps W16q+W16k (dead after projections)
  float* colsum = (float*)(ws);

  cvt_f16<<<1024, 256, 0, stream>>>(Wq, W16q, 262144);
  cvt_f16<<<1024, 256, 0, stream>>>(Wk, W16k, 262144);
  cvt_f16<<<1024, 256, 0, stream>>>(Wv, W16v, 262144);

  // Q [C x Pk] natural; K,V transposed [P x C]
  proj_q <<<dim3(8, 2, 32), 256, 0, stream>>>(Xk, W16q, bq, Q16, 1024);
  proj_kv<<<dim3(2, 8, 32), 256, 0, stream>>>(Xk, W16k, bk, Kt16, 1024);
  proj_kv<<<dim3(2, 32, 32), 256, 0, stream>>>(Xq, W16v, bv, Vt16, 4096);

  // expS = exp(K^T V * (1/32)) -> Hout region (f32), plus column partial sums
  gemm_nt_t<2><<<dim3(32, 8, 8), 256, 0, stream>>>(Kt16, Vt16, Hout, 1024, 4096,
      1048576L, 4194304L, 4194304L, 0.03125f, colsum);

  // H = expS / L (in place), emit H16 and H16^T
  h_finalize<<<dim3(64, 16, 8), 256, 0, stream>>>(Hout, colsum, H16, H16t);

  // out = Q * H   (A = Q [C x Pk], B = H^T [Pq x Pk])
  gemm_nt_t<0><<<dim3(32, 8, 8), 256, 0, stream>>>(Q16, H16t, out, 1024, 4096,
      1048576L, 4194304L, 4194304L, 1.0f, nullptr);

  // sparse loss: mean((H H^T - I)^2), upper triangle only (x2 off-diagonal)
  gemm_nt_t<1><<<dim3(8, 8, 8), 256, 0, stream>>>(H16, H16, nullptr, 4096, 0,
      4194304L, 4194304L, 0L, 1.0f, parts);
  finalize_k<<<1, 256, 0, stream>>>(parts, loss_out);
}

// Round 3
// 538.134 us; speedup vs baseline: 1.2176x; 1.0312x over previous
//
#include <hip/hip_runtime.h>

typedef _Float16 f16;
typedef f16 f16x8 __attribute__((ext_vector_type(8)));
typedef float f32x4 __attribute__((ext_vector_type(4)));

// async global->LDS, 16B per lane; lds ptr must be wave-uniform base (HW adds lane*16)
__device__ __forceinline__ void gload16(const void* g, void* ldsbase) {
  __builtin_amdgcn_global_load_lds((const __attribute__((address_space(1))) unsigned int*)g,
                                   (__attribute__((address_space(3))) unsigned int*)ldsbase, 16, 0, 0);
}

// swizzled byte offset of 16B chunk c (k-chunk) of row `row` in a [rows][32] f16 tile
__device__ __forceinline__ int swz(int row, int c) {
  return row * 64 + ((c ^ ((row >> 1) & 3)) << 4);
}

// ---------------- generic NT GEMM: A [M x K] f16, B [N x K] f16
// MODE 1: Gram loss partials, compact upper-triangle grid (A==B), identity subtracted
// MODE 2: E = exp(A*B^T * scale) -> E16 [M x N] and E16t [N x M] (f16), col partial sums
// MODE 3: C = (A*B^T) * inv[col]  (f32)
template<int MODE>
__global__ void __launch_bounds__(256)
gemm_nt_t(const f16* __restrict__ A, const f16* __restrict__ Bm, float* __restrict__ C,
          f16* __restrict__ E16, f16* __restrict__ E16t,
          int K, int ldc, long sA, long sB, long sC, float scale,
          float* __restrict__ parts, const float* __restrict__ inv) {
  const int t = threadIdx.x, l = t & 63, w = t >> 6, wr = w >> 1, wc = w & 1;
  int bx = blockIdx.x, by = blockIdx.y;
  if (MODE == 1) {  // compact upper-triangle: q -> (by, bx) with bx >= by
    int r = bx; by = 0;
    while (r >= 8 - by) { r -= 8 - by; ++by; }
    bx = by + r;
  }
  __shared__ f16 sb[8192];
  f16* As = sb;
  f16* Bs = sb + 4096;
  const long b = blockIdx.z;
  const f16* Ab = A + b * sA + (long)(by * 128) * K;
  const f16* Bb = Bm + b * sB + (long)(bx * 128) * K;
  const int r0 = t >> 2, cs = (t & 3) ^ ((r0 >> 1) & 3);
  const f16* aS0 = Ab + (long)r0 * K + cs * 8;
  const f16* aS1 = Ab + (long)(r0 + 64) * K + cs * 8;
  const f16* bS0 = Bb + (long)r0 * K + cs * 8;
  const f16* bS1 = Bb + (long)(r0 + 64) * K + cs * 8;
  int offA[4], offB[4];
#pragma unroll
  for (int i = 0; i < 4; ++i) {
    int ra = wr * 64 + i * 16 + (l & 15);
    offA[i] = swz(ra, l >> 4);
    int rb = wc * 64 + i * 16 + (l & 15);
    offB[i] = swz(rb, l >> 4);
  }
  f32x4 acc[4][4] = {};
  for (int k0 = 0; k0 < K; k0 += 32) {
    gload16(aS0 + k0, As + w * 512);
    gload16(aS1 + k0, As + 2048 + w * 512);
    gload16(bS0 + k0, Bs + w * 512);
    gload16(bS1 + k0, Bs + 2048 + w * 512);
    __syncthreads();
    f16x8 af[4], bf[4];
#pragma unroll
    for (int i = 0; i < 4; ++i) {
      af[i] = *(const f16x8*)((const char*)As + offA[i]);
      bf[i] = *(const f16x8*)((const char*)Bs + offB[i]);
    }
#pragma unroll
    for (int mi = 0; mi < 4; ++mi)
#pragma unroll
      for (int ni = 0; ni < 4; ++ni)
        acc[mi][ni] = __builtin_amdgcn_mfma_f32_16x16x32_f16(af[mi], bf[ni], acc[mi][ni], 0, 0, 0);
    __syncthreads();
  }
  if (MODE == 2) {
    // overwrite acc with e = exp(acc*scale), accumulate per-column sums
    float csum[4] = {};
#pragma unroll
    for (int mi = 0; mi < 4; ++mi)
#pragma unroll
      for (int ni = 0; ni < 4; ++ni)
#pragma unroll
        for (int q = 0; q < 4; ++q) {
          float e = __expf(acc[mi][ni][q] * scale);
          acc[mi][ni][q] = e;
          csum[ni] += e;
        }
#pragma unroll
    for (int ni = 0; ni < 4; ++ni) {
      csum[ni] += __shfl_xor(csum[ni], 16);
      csum[ni] += __shfl_xor(csum[ni], 32);
    }
    __shared__ float colp[2][128];
    if (l < 16) {
#pragma unroll
      for (int ni = 0; ni < 4; ++ni) colp[wr][wc * 64 + ni * 16 + l] = csum[ni];
    }
    const long i0 = by * 128, j0 = bx * 128;
    // E16 row-major, two 64-row chunks bounced through sb [64][128]
#pragma unroll
    for (int ck = 0; ck < 2; ++ck) {
      if (wr == ck) {
#pragma unroll
        for (int mi = 0; mi < 4; ++mi)
#pragma unroll
          for (int ni = 0; ni < 4; ++ni)
#pragma unroll
            for (int q = 0; q < 4; ++q)
              sb[(mi * 16 + (l >> 4) * 4 + q) * 128 + wc * 64 + ni * 16 + (l & 15)] = (f16)acc[mi][ni][q];
      }
      __syncthreads();
      if (ck == 0 && t < 128)
        parts[(b * 8 + by) * 4096 + bx * 128 + t] = colp[0][t] + colp[1][t];
#pragma unroll
      for (int p = 0; p < 4; ++p) {
        int row = (t >> 4) + p * 16;
        *(f16x8*)(E16 + b * 4194304L + (i0 + ck * 64 + row) * 4096L + j0 + (t & 15) * 8) =
            *(f16x8*)(sb + row * 128 + (t & 15) * 8);
      }
      __syncthreads();
    }
    // E16t [N x M], two 64-col chunks
#pragma unroll
    for (int ck = 0; ck < 2; ++ck) {
      if (wc == ck) {
#pragma unroll
        for (int mi = 0; mi < 4; ++mi)
#pragma unroll
          for (int ni = 0; ni < 4; ++ni)
#pragma unroll
            for (int q = 0; q < 4; ++q)
              sb[(ni * 16 + (l & 15)) * 128 + wr * 64 + mi * 16 + (l >> 4) * 4 + q] = (f16)acc[mi][ni][q];
      }
      __syncthreads();
#pragma unroll
      for (int p = 0; p < 4; ++p) {
        int row = (t >> 4) + p * 16;  // local j
        *(f16x8*)(E16t + b * 4194304L + (j0 + ck * 64 + row) * 1024L + i0 + (t & 15) * 8) =
            *(f16x8*)(sb + row * 128 + (t & 15) * 8);
      }
      __syncthreads();
    }
  } else if (MODE == 3) {
    float* Cb = C + b * sC + (long)(by * 128 + wr * 64) * ldc + bx * 128 + wc * 64;
    const float* ip = inv + b * 4096 + bx * 128 + wc * 64;
    float iv[4];
#pragma unroll
    for (int ni = 0; ni < 4; ++ni) iv[ni] = ip[ni * 16 + (l & 15)];
#pragma unroll
    for (int mi = 0; mi < 4; ++mi)
#pragma unroll
      for (int ni = 0; ni < 4; ++ni)
#pragma unroll
        for (int q = 0; q < 4; ++q)
          Cb[(long)(mi * 16 + (l >> 4) * 4 + q) * ldc + ni * 16 + (l & 15)] = acc[mi][ni][q] * iv[ni];
  } else {  // MODE 1: Gram loss
    const float wgt = (bx == by) ? 1.f : 2.f;
    const int gr0 = by * 128 + wr * 64 + (l >> 4) * 4;
    const int gc0 = bx * 128 + wc * 64 + (l & 15);
    float p = 0.f;
#pragma unroll
    for (int mi = 0; mi < 4; ++mi)
#pragma unroll
      for (int ni = 0; ni < 4; ++ni)
#pragma unroll
        for (int q = 0; q < 4; ++q) {
          float e = acc[mi][ni][q];
          if (gr0 + mi * 16 + q == gc0 + ni * 16) e -= 1.f;
          p += e * e;
        }
    p *= wgt;
#pragma unroll
    for (int d = 32; d; d >>= 1) p += __shfl_down(p, d);
    __shared__ float red[4];
    if (l == 0) red[w] = p;
    __syncthreads();
    if (t == 0) parts[blockIdx.x + 36 * blockIdx.z] = red[0] + red[1] + red[2] + red[3];
  }
}

// ---------------- projection, output natural [C x P]: Q[o,p] = sum_i W[o,i] X[i,p] + b[o]
__global__ void __launch_bounds__(256)
proj_q(const float* __restrict__ X, const f16* __restrict__ W16, const float* __restrict__ bias,
       f16* __restrict__ Q, int P) {
  __shared__ f16 As[4096], Bs[4096];  // As = W [o][i], Bs = Xt [p][i]
  const int t = threadIdx.x, l = t & 63, w = t >> 6, wr = w >> 1, wc = w & 1;
  const int bg = blockIdx.z, g = bg & 3;
  const long b = bg >> 2;
  const int p0 = blockIdx.x * 128, m0 = blockIdx.y * 128;
  const float* Xb = X + b * 1024 * P + (long)g * 256 * P;
  const f16* Wg = W16 + g * 65536 + m0 * 256;
  const int r0 = t >> 2, cs = (t & 3) ^ ((r0 >> 1) & 3);
  const f16* wS0 = Wg + r0 * 256 + cs * 8;
  const f16* wS1 = Wg + (r0 + 64) * 256 + cs * 8;
  const int xp = t & 63, xc = t >> 6;
  const float* xS = Xb + (long)(xc * 8) * P + p0 + xp;
  const int xo0 = swz(xp, xc), xo1 = swz(xp + 64, xc);
  int offA[4], offB[4];
#pragma unroll
  for (int i = 0; i < 4; ++i) {
    int ra = wr * 64 + i * 16 + (l & 15);
    offA[i] = swz(ra, l >> 4);
    int rb = wc * 64 + i * 16 + (l & 15);
    offB[i] = swz(rb, l >> 4);
  }
  f32x4 acc[4][4] = {};
  for (int k0 = 0; k0 < 256; k0 += 32) {
    gload16(wS0 + k0, As + w * 512);
    gload16(wS1 + k0, As + 2048 + w * 512);
    const float* xs = xS + (long)k0 * P;
    f16x8 v0, v1;
#pragma unroll
    for (int d = 0; d < 8; ++d) v0[d] = (f16)xs[(long)d * P];
#pragma unroll
    for (int d = 0; d < 8; ++d) v1[d] = (f16)xs[(long)d * P + 64];
    *(f16x8*)((char*)Bs + xo0) = v0;
    *(f16x8*)((char*)Bs + xo1) = v1;
    __syncthreads();
    f16x8 af[4], bf[4];
#pragma unroll
    for (int i = 0; i < 4; ++i) {
      af[i] = *(const f16x8*)((const char*)As + offA[i]);
      bf[i] = *(const f16x8*)((const char*)Bs + offB[i]);
    }
#pragma unroll
    for (int mi = 0; mi < 4; ++mi)
#pragma unroll
      for (int ni = 0; ni < 4; ++ni)
        acc[mi][ni] = __builtin_amdgcn_mfma_f32_16x16x32_f16(af[mi], bf[ni], acc[mi][ni], 0, 0, 0);
    __syncthreads();
  }
  f16* Qb = Q + b * 1048576 + (long)(g * 256 + m0 + wr * 64) * 1024 + p0 + wc * 64;
#pragma unroll
  for (int mi = 0; mi < 4; ++mi)
#pragma unroll
    for (int q = 0; q < 4; ++q) {
      float bv = bias[g * 256 + m0 + wr * 64 + mi * 16 + (l >> 4) * 4 + q];
#pragma unroll
      for (int ni = 0; ni < 4; ++ni)
        Qb[(long)(mi * 16 + (l >> 4) * 4 + q) * 1024 + ni * 16 + (l & 15)] = (f16)(acc[mi][ni][q] + bv);
    }
}

// ---------------- projection, output transposed [P x C]: Yt[p,c] = sum_i X[i,p] W[o,i] + b[c]
__global__ void __launch_bounds__(256)
proj_kv(const float* __restrict__ X, const f16* __restrict__ W16, const float* __restrict__ bias,
        f16* __restrict__ Yt, int P) {
  __shared__ f16 As[4096], Bs[4096];  // As = Xt [p][i], Bs = W [o][i]
  const int t = threadIdx.x, l = t & 63, w = t >> 6, wr = w >> 1, wc = w & 1;
  const int bg = blockIdx.z, g = bg & 3;
  const long b = bg >> 2;
  const int p0 = blockIdx.y * 128, n0 = blockIdx.x * 128;
  const float* Xb = X + b * 1024 * P + (long)g * 256 * P;
  const f16* Wg = W16 + g * 65536 + n0 * 256;
  const int r0 = t >> 2, cs = (t & 3) ^ ((r0 >> 1) & 3);
  const f16* wS0 = Wg + r0 * 256 + cs * 8;
  const f16* wS1 = Wg + (r0 + 64) * 256 + cs * 8;
  const int xp = t & 63, xc = t >> 6;
  const float* xS = Xb + (long)(xc * 8) * P + p0 + xp;
  const int xo0 = swz(xp, xc), xo1 = swz(xp + 64, xc);
  int offA[4], offB[4];
#pragma unroll
  for (int i = 0; i < 4; ++i) {
    int ra = wr * 64 + i * 16 + (l & 15);
    offA[i] = swz(ra, l >> 4);
    int rb = wc * 64 + i * 16 + (l & 15);
    offB[i] = swz(rb, l >> 4);
  }
  f32x4 acc[4][4] = {};
  for (int k0 = 0; k0 < 256; k0 += 32) {
    gload16(wS0 + k0, Bs + w * 512);
    gload16(wS1 + k0, Bs + 2048 + w * 512);
    const float* xs = xS + (long)k0 * P;
    f16x8 v0, v1;
#pragma unroll
    for (int d = 0; d < 8; ++d) v0[d] = (f16)xs[(long)d * P];
#pragma unroll
    for (int d = 0; d < 8; ++d) v1[d] = (f16)xs[(long)d * P + 64];
    *(f16x8*)((char*)As + xo0) = v0;
    *(f16x8*)((char*)As + xo1) = v1;
    __syncthreads();
    f16x8 af[4], bf[4];
#pragma unroll
    for (int i = 0; i < 4; ++i) {
      af[i] = *(const f16x8*)((const char*)As + offA[i]);
      bf[i] = *(const f16x8*)((const char*)Bs + offB[i]);
    }
#pragma unroll
    for (int mi = 0; mi < 4; ++mi)
#pragma unroll
      for (int ni = 0; ni < 4; ++ni)
        acc[mi][ni] = __builtin_amdgcn_mfma_f32_16x16x32_f16(af[mi], bf[ni], acc[mi][ni], 0, 0, 0);
    __syncthreads();
  }
  f16* Yb = Yt + b * P * 1024 + (long)(p0 + wr * 64) * 1024 + g * 256 + n0 + wc * 64;
  float bcol[4];
#pragma unroll
  for (int ni = 0; ni < 4; ++ni) bcol[ni] = bias[g * 256 + n0 + wc * 64 + ni * 16 + (l & 15)];
#pragma unroll
  for (int mi = 0; mi < 4; ++mi)
#pragma unroll
    for (int q = 0; q < 4; ++q)
#pragma unroll
      for (int ni = 0; ni < 4; ++ni)
        Yb[(long)(mi * 16 + (l >> 4) * 4 + q) * 1024 + ni * 16 + (l & 15)] = (f16)(acc[mi][ni][q] + bcol[ni]);
}

// ---------------- inv[b][j] = 1 / sum_my colsum[b][my][j]
__global__ void __launch_bounds__(256)
inv_k(const float* __restrict__ colsum, float* __restrict__ inv) {
  int gid = blockIdx.x * 256 + threadIdx.x;  // 8*4096
  int b = gid >> 12, j = gid & 4095;
  const float* cp = colsum + (long)(b * 8) * 4096 + j;
  float s = 0.f;
#pragma unroll
  for (int my = 0; my < 8; ++my) s += cp[my * 4096];
  inv[gid] = 1.f / s;
}

// ---------------- streaming finalize: H f32 = E16*inv -> Hf; E16 <- H16 (in place)
__global__ void __launch_bounds__(256)
h_finalize2(f16* __restrict__ E, float* __restrict__ Hf, const float* __restrict__ inv) {
  for (long g = blockIdx.x * 256L + threadIdx.x; g < 4194304L; g += (long)gridDim.x * 256) {
    long idx8 = g * 8;
    int b = (int)(idx8 >> 22);
    int j = (int)(idx8 & 4095);
    f16x8 e = *(f16x8*)(E + idx8);
    const float* ip = inv + (b << 12) + j;
    f32x4 i0 = *(const f32x4*)ip;
    f32x4 i1 = *(const f32x4*)(ip + 4);
    float h[8];
    f16x8 o;
#pragma unroll
    for (int k = 0; k < 8; ++k) {
      float iv = (k < 4) ? i0[k] : i1[k - 4];
      h[k] = (float)e[k] * iv;
      o[k] = (f16)h[k];
    }
    *(f16x8*)(E + idx8) = o;
    float* hp = Hf + idx8;  // base is only 4B-aligned (out+1 float): scalar stores
#pragma unroll
    for (int k = 0; k < 8; ++k) hp[k] = h[k];
  }
}

__global__ void cvt_f16(const float* __restrict__ s, f16* __restrict__ d, int n) {
  int i = blockIdx.x * 256 + threadIdx.x;
  if (i < n) d[i] = (f16)s[i];
}

__global__ void __launch_bounds__(256)
finalize_k(const float* __restrict__ parts, float* __restrict__ o) {
  const int t = threadIdx.x;
  float s = 0.f;
  for (int i = t; i < 288; i += 256) s += parts[i];
#pragma unroll
  for (int d = 32; d; d >>= 1) s += __shfl_down(s, d);
  __shared__ float red[4];
  if ((t & 63) == 0) red[t >> 6] = s;
  __syncthreads();
  if (t == 0) *o = (red[0] + red[1] + red[2] + red[3]) * (1.0f / 8388608.0f);
}

extern "C" void kernel_launch(void* const* d_in, const int* in_sizes, int n_in,
                              void* d_out, int out_size, void* d_ws, size_t ws_size,
                              hipStream_t stream) {
  const float* Xq = (const float*)d_in[0];
  const float* Xk = (const float*)d_in[1];
  const float* Wq = (const float*)d_in[2];
  const float* bq = (const float*)d_in[3];
  const float* Wk = (const float*)d_in[4];
  const float* bk = (const float*)d_in[5];
  const float* Wv = (const float*)d_in[6];
  const float* bv = (const float*)d_in[7];
  float* out = (float*)d_out;
  float* loss_out = out + 33554432;
  float* Hf = out + 33554433;  // H f32 output [8][1024][4096]

  char* ws = (char*)d_ws;
  f16* W16q = (f16*)(ws);
  f16* W16k = (f16*)(ws + (1 << 19));
  f16* W16v = (f16*)(ws + 2L * (1 << 19));
  f16* Q16  = (f16*)(ws + 3L * (1 << 19));                                  // [8][1024][1024]
  f16* Kt16 = (f16*)(ws + 3L * (1 << 19) + (1L << 24));                     // [8][1024][1024]
  f16* Vt16 = (f16*)(ws + 3L * (1 << 19) + 2L * (1 << 24));                 // [8][4096][1024]
  f16* E16  = (f16*)(ws + 3L * (1 << 19) + 2L * (1 << 24) + (1L << 26));    // [8][1024][4096] -> becomes H16
  f16* E16t = (f16*)(ws + 3L * (1 << 19) + 2L * (1 << 24) + 2L * (1 << 26));// [8][4096][1024]
  float* parts = (float*)(ws + 3L * (1 << 19) + 2L * (1 << 24) + 3L * (1 << 26)); // 288 f32
  float* invb  = (float*)(ws + 3L * (1 << 19) + 2L * (1 << 24) + 3L * (1 << 26) + 8192); // [8][4096]
  // colsum [8][8][4096] f32 = 1 MB, overlaps W16q+W16k (dead after projections)
  float* colsum = (float*)(ws);

  cvt_f16<<<1024, 256, 0, stream>>>(Wq, W16q, 262144);
  cvt_f16<<<1024, 256, 0, stream>>>(Wk, W16k, 262144);
  cvt_f16<<<1024, 256, 0, stream>>>(Wv, W16v, 262144);

  // Q [C x Pk] natural; K,V transposed [P x C]
  proj_q <<<dim3(8, 2, 32), 256, 0, stream>>>(Xk, W16q, bq, Q16, 1024);
  proj_kv<<<dim3(2, 8, 32), 256, 0, stream>>>(Xk, W16k, bk, Kt16, 1024);
  proj_kv<<<dim3(2, 32, 32), 256, 0, stream>>>(Xq, W16v, bv, Vt16, 4096);

  // E = exp(K^T V /32) -> E16 + E16t (f16) + column partial sums
  gemm_nt_t<2><<<dim3(32, 8, 8), 256, 0, stream>>>(Kt16, Vt16, nullptr, E16, E16t,
      1024, 4096, 1048576L, 4194304L, 4194304L, 0.03125f, colsum, nullptr);

  inv_k<<<128, 256, 0, stream>>>(colsum, invb);

  // H f32 -> d_out, E16 -> H16 in place
  h_finalize2<<<2048, 256, 0, stream>>>(E16, Hf, invb);

  // out = Q * H = (Q * E^T) * inv[col]
  gemm_nt_t<3><<<dim3(32, 8, 8), 256, 0, stream>>>(Q16, E16t, out, nullptr, nullptr,
      1024, 4096, 1048576L, 4194304L, 4194304L, 1.0f, nullptr, invb);

  // sparse loss: mean((H H^T - I)^2), compact upper triangle (x2 off-diagonal)
  gemm_nt_t<1><<<dim3(36, 1, 8), 256, 0, stream>>>(E16, E16, nullptr, nullptr, nullptr,
      4096, 0, 4194304L, 4194304L, 0L, 1.0f, parts, nullptr);
  finalize_k<<<1, 256, 0, stream>>>(parts, loss_out);
}

// Round 4
// 468.379 us; speedup vs baseline: 1.3989x; 1.1489x over previous
//
#include <hip/hip_runtime.h>

typedef _Float16 f16;
typedef f16 f16x8 __attribute__((ext_vector_type(8)));
typedef float f32x4 __attribute__((ext_vector_type(4)));

// async global->LDS, 16B per lane; lds ptr must be wave-uniform base (HW adds lane*16)
__device__ __forceinline__ void gload16(const void* g, void* ldsbase) {
  __builtin_amdgcn_global_load_lds((const __attribute__((address_space(1))) unsigned int*)g,
                                   (__attribute__((address_space(3))) unsigned int*)ldsbase, 16, 0, 0);
}

// swizzled byte offset of 16B chunk c (k-chunk) of row `row` in a [rows][32] f16 tile (BK=32 kernels)
__device__ __forceinline__ int swz(int row, int c) {
  return row * 64 + ((c ^ ((row >> 1) & 3)) << 4);
}

// ================= 256x256 tile, BK=64, 512 threads, counted-vmcnt schedule =================
// NT GEMM: A [M x K], B [N x K] f16, K-contiguous. M=1024 (by: 4), N=4096 (bx: 16), batch 8.
// MODE 2: E = exp(A*B^T * scale) -> E16 [M x N] + E16t [N x M] + column partial sums (aux)
// MODE 3: C = (A*B^T) * aux[col]  (f32)
template<int MODE>
__global__ void __launch_bounds__(512, 2)
gemm256(const f16* __restrict__ A, const f16* __restrict__ Bm, float* __restrict__ Cf,
        f16* __restrict__ E16, f16* __restrict__ E16t,
        int K, long sA, long sB, float scale, float* __restrict__ aux) {
  __shared__ f16 sb[65536];  // 128 KB: A0[16384] B0[16384] A1[16384] B1[16384]
  const int t = threadIdx.x, l = t & 63, w = t >> 6;
  const int wr = w >> 2, wc = w & 3;
  const int bid = blockIdx.x;
  const int swzb = (bid & 7) * 64 + (bid >> 3);  // XCD-chunked (512 % 8 == 0)
  const long b = swzb >> 6;
  const int by = (swzb >> 4) & 3, bx = swzb & 15;
  const char* Abyte = (const char*)(A + b * sA + (long)(by * 256) * K);
  const char* Bbyte = (const char*)(Bm + b * sB + (long)(bx * 256) * K);

  // staging source byte-offsets (pre-swizzled source, linear LDS dest)
  int offSrc[4];
#pragma unroll
  for (int i = 0; i < 4; ++i) {
    int cid = i * 512 + t, row = cid >> 3, slot = cid & 7;
    offSrc[i] = row * (K * 2) + ((slot ^ (row & 7)) << 4);
  }
  // fragment element-offsets in the [256][64] swizzled tile
  int offAf[8][2], offBf[4][2];
#pragma unroll
  for (int mi = 0; mi < 8; ++mi) {
    int r = wr * 128 + mi * 16 + (l & 15);
#pragma unroll
    for (int ks = 0; ks < 2; ++ks)
      offAf[mi][ks] = r * 64 + ((((ks << 2) + (l >> 4)) ^ (r & 7)) << 3);
  }
#pragma unroll
  for (int ni = 0; ni < 4; ++ni) {
    int r = wc * 64 + ni * 16 + (l & 15);
#pragma unroll
    for (int ks = 0; ks < 2; ++ks)
      offBf[ni][ks] = r * 64 + ((((ks << 2) + (l >> 4)) ^ (r & 7)) << 3);
  }

  const int NT = K >> 6;
  f32x4 acc[8][4] = {};

  auto STAGE = [&](int kt, int bsel) {
    f16* la = sb + bsel * 32768;
    f16* lb = la + 16384;
    const char* as = Abyte + (long)kt * 128;
    const char* bs = Bbyte + (long)kt * 128;
#pragma unroll
    for (int i = 0; i < 4; ++i)
      gload16(as + offSrc[i], la + (i * 512 + (w << 6)) * 8);
#pragma unroll
    for (int i = 0; i < 4; ++i)
      gload16(bs + offSrc[i], lb + (i * 512 + (w << 6)) * 8);
  };

  STAGE(0, 0);
  for (int kt = 0; kt < NT; ++kt) {
    const int cur = kt & 1;
    if (kt + 1 < NT) {
      STAGE(kt + 1, cur ^ 1);
      asm volatile("s_waitcnt vmcnt(8)" ::: "memory");  // kt's 8 loads done; kt+1's 8 in flight
    } else {
      asm volatile("s_waitcnt vmcnt(0)" ::: "memory");
    }
    __builtin_amdgcn_s_barrier();
    asm volatile("" ::: "memory");
    const f16* la = sb + cur * 32768;
    const f16* lb = la + 16384;
#pragma unroll
    for (int ks = 0; ks < 2; ++ks) {
      f16x8 bf[4];
#pragma unroll
      for (int ni = 0; ni < 4; ++ni) bf[ni] = *(const f16x8*)(lb + offBf[ni][ks]);
#pragma unroll
      for (int mi = 0; mi < 8; ++mi) {
        f16x8 af = *(const f16x8*)(la + offAf[mi][ks]);
#pragma unroll
        for (int ni = 0; ni < 4; ++ni)
          acc[mi][ni] = __builtin_amdgcn_mfma_f32_16x16x32_f16(af, bf[ni], acc[mi][ni], 0, 0, 0);
      }
    }
    asm volatile("s_waitcnt lgkmcnt(0)" ::: "memory");
    __builtin_amdgcn_s_barrier();
    asm volatile("" ::: "memory");
  }

  const int i0 = by * 256, j0 = bx * 256;
  if (MODE == 2) {
    float csum[4] = {};
#pragma unroll
    for (int mi = 0; mi < 8; ++mi)
#pragma unroll
      for (int ni = 0; ni < 4; ++ni)
#pragma unroll
        for (int q = 0; q < 4; ++q) {
          float e = __expf(acc[mi][ni][q] * scale);
          acc[mi][ni][q] = e;
          csum[ni] += e;
        }
#pragma unroll
    for (int ni = 0; ni < 4; ++ni) {
      csum[ni] += __shfl_xor(csum[ni], 16);
      csum[ni] += __shfl_xor(csum[ni], 32);
    }
    float* colp = (float*)(sb + 34816);  // past the 64x264 slab region
    if (l < 16) {
#pragma unroll
      for (int ni = 0; ni < 4; ++ni) colp[wr * 256 + wc * 64 + ni * 16 + l] = csum[ni];
    }
    __syncthreads();
    if (t < 256) aux[(b * 4 + by) * 4096 + bx * 256 + t] = colp[t] + colp[256 + t];
    f16* E16b = E16 + b * 4194304L;
    f16* E16tb = E16t + b * 4194304L;
#pragma unroll
    for (int s = 0; s < 4; ++s) {
      if (wr == (s >> 1)) {  // slab s = rows [s*64, s*64+64) of the tile, padded stride 264
        const int h = s & 1;
#pragma unroll
        for (int m2 = 0; m2 < 4; ++m2)
#pragma unroll
          for (int ni = 0; ni < 4; ++ni)
#pragma unroll
            for (int q = 0; q < 4; ++q)
              sb[(m2 * 16 + (l >> 4) * 4 + q) * 264 + wc * 64 + ni * 16 + (l & 15)] =
                  (f16)acc[h * 4 + m2][ni][q];
      }
      __syncthreads();
#pragma unroll
      for (int ii = 0; ii < 4; ++ii) {  // E16 row-major readout, coalesced 16B
        int cid = ii * 512 + t, r = cid >> 5, cc = cid & 31;
        *(f16x8*)(E16b + (long)(i0 + s * 64 + r) * 4096 + j0 + cc * 8) =
            *(const f16x8*)(sb + r * 264 + cc * 8);
      }
      const int q4 = w >> 1, r8 = l >> 3, ic = l & 7;
#pragma unroll
      for (int ii = 0; ii < 4; ++ii) {  // E16t: column gather (bank-balanced), 16B stores
        int j = q4 * 64 + r8 * 8 + (w & 1) * 4 + ii;
        f16x8 v;
#pragma unroll
        for (int k2 = 0; k2 < 8; ++k2) v[k2] = sb[(ic * 8 + k2) * 264 + j];
        *(f16x8*)(E16tb + (long)(j0 + j) * 1024 + i0 + s * 64 + ic * 8) = v;
      }
      __syncthreads();
    }
  } else {  // MODE 3
    const float* ip = aux + b * 4096 + bx * 256 + wc * 64;
    float iv[4];
#pragma unroll
    for (int ni = 0; ni < 4; ++ni) iv[ni] = ip[ni * 16 + (l & 15)];
    float* Cb = Cf + b * 4194304L + (long)(by * 256 + wr * 128) * 4096 + bx * 256 + wc * 64;
#pragma unroll
    for (int mi = 0; mi < 8; ++mi)
#pragma unroll
      for (int ni = 0; ni < 4; ++ni)
#pragma unroll
        for (int q = 0; q < 4; ++q)
          Cb[(long)(mi * 16 + (l >> 4) * 4 + q) * 4096 + ni * 16 + (l & 15)] = acc[mi][ni][q] * iv[ni];
  }
}

// ================= 128x128 Gram-loss kernel (K=4096), compact upper triangle =================
__global__ void __launch_bounds__(256)
gram_k(const f16* __restrict__ A, int K, long sA, float* __restrict__ parts) {
  const int t = threadIdx.x, l = t & 63, w = t >> 6, wr = w >> 1, wc = w & 1;
  int bx = blockIdx.x, by = 0;
  {
    int r = bx;
    while (r >= 8 - by) { r -= 8 - by; ++by; }
    bx = by + r;
  }
  __shared__ f16 As[4096], Bs[4096];
  const long b = blockIdx.z;
  const f16* Ab = A + b * sA + (long)(by * 128) * K;
  const f16* Bb = A + b * sA + (long)(bx * 128) * K;
  const int r0 = t >> 2, cs = (t & 3) ^ ((r0 >> 1) & 3);
  const f16* aS0 = Ab + (long)r0 * K + cs * 8;
  const f16* aS1 = Ab + (long)(r0 + 64) * K + cs * 8;
  const f16* bS0 = Bb + (long)r0 * K + cs * 8;
  const f16* bS1 = Bb + (long)(r0 + 64) * K + cs * 8;
  int offA[4], offB[4];
#pragma unroll
  for (int i = 0; i < 4; ++i) {
    int ra = wr * 64 + i * 16 + (l & 15);
    offA[i] = swz(ra, l >> 4);
    int rb = wc * 64 + i * 16 + (l & 15);
    offB[i] = swz(rb, l >> 4);
  }
  f32x4 acc[4][4] = {};
  for (int k0 = 0; k0 < K; k0 += 32) {
    gload16(aS0 + k0, As + w * 512);
    gload16(aS1 + k0, As + 2048 + w * 512);
    gload16(bS0 + k0, Bs + w * 512);
    gload16(bS1 + k0, Bs + 2048 + w * 512);
    __syncthreads();
    f16x8 af[4], bf[4];
#pragma unroll
    for (int i = 0; i < 4; ++i) {
      af[i] = *(const f16x8*)((const char*)As + offA[i]);
      bf[i] = *(const f16x8*)((const char*)Bs + offB[i]);
    }
#pragma unroll
    for (int mi = 0; mi < 4; ++mi)
#pragma unroll
      for (int ni = 0; ni < 4; ++ni)
        acc[mi][ni] = __builtin_amdgcn_mfma_f32_16x16x32_f16(af[mi], bf[ni], acc[mi][ni], 0, 0, 0);
    __syncthreads();
  }
  const float wgt = (bx == by) ? 1.f : 2.f;
  const int gr0 = by * 128 + wr * 64 + (l >> 4) * 4;
  const int gc0 = bx * 128 + wc * 64 + (l & 15);
  float p = 0.f;
#pragma unroll
  for (int mi = 0; mi < 4; ++mi)
#pragma unroll
    for (int ni = 0; ni < 4; ++ni)
#pragma unroll
      for (int q = 0; q < 4; ++q) {
        float e = acc[mi][ni][q];
        if (gr0 + mi * 16 + q == gc0 + ni * 16) e -= 1.f;
        p += e * e;
      }
  p *= wgt;
#pragma unroll
  for (int d = 32; d; d >>= 1) p += __shfl_down(p, d);
  __shared__ float red[4];
  if (l == 0) red[w] = p;
  __syncthreads();
  if (t == 0) parts[blockIdx.x + 36 * blockIdx.z] = red[0] + red[1] + red[2] + red[3];
}

// ---------------- projection, output natural [C x P]: Q[o,p] = sum_i W[o,i] X[i,p] + b[o]
__global__ void __launch_bounds__(256)
proj_q(const float* __restrict__ X, const f16* __restrict__ W16, const float* __restrict__ bias,
       f16* __restrict__ Q, int P) {
  __shared__ f16 As[4096], Bs[4096];  // As = W [o][i], Bs = Xt [p][i]
  const int t = threadIdx.x, l = t & 63, w = t >> 6, wr = w >> 1, wc = w & 1;
  const int bg = blockIdx.z, g = bg & 3;
  const long b = bg >> 2;
  const int p0 = blockIdx.x * 128, m0 = blockIdx.y * 128;
  const float* Xb = X + b * 1024 * P + (long)g * 256 * P;
  const f16* Wg = W16 + g * 65536 + m0 * 256;
  const int r0 = t >> 2, cs = (t & 3) ^ ((r0 >> 1) & 3);
  const f16* wS0 = Wg + r0 * 256 + cs * 8;
  const f16* wS1 = Wg + (r0 + 64) * 256 + cs * 8;
  const int xp = t & 63, xc = t >> 6;
  const float* xS = Xb + (long)(xc * 8) * P + p0 + xp;
  const int xo0 = swz(xp, xc), xo1 = swz(xp + 64, xc);
  int offA[4], offB[4];
#pragma unroll
  for (int i = 0; i < 4; ++i) {
    int ra = wr * 64 + i * 16 + (l & 15);
    offA[i] = swz(ra, l >> 4);
    int rb = wc * 64 + i * 16 + (l & 15);
    offB[i] = swz(rb, l >> 4);
  }
  f32x4 acc[4][4] = {};
  for (int k0 = 0; k0 < 256; k0 += 32) {
    gload16(wS0 + k0, As + w * 512);
    gload16(wS1 + k0, As + 2048 + w * 512);
    const float* xs = xS + (long)k0 * P;
    f16x8 v0, v1;
#pragma unroll
    for (int d = 0; d < 8; ++d) v0[d] = (f16)xs[(long)d * P];
#pragma unroll
    for (int d = 0; d < 8; ++d) v1[d] = (f16)xs[(long)d * P + 64];
    *(f16x8*)((char*)Bs + xo0) = v0;
    *(f16x8*)((char*)Bs + xo1) = v1;
    __syncthreads();
    f16x8 af[4], bf[4];
#pragma unroll
    for (int i = 0; i < 4; ++i) {
      af[i] = *(const f16x8*)((const char*)As + offA[i]);
      bf[i] = *(const f16x8*)((const char*)Bs + offB[i]);
    }
#pragma unroll
    for (int mi = 0; mi < 4; ++mi)
#pragma unroll
      for (int ni = 0; ni < 4; ++ni)
        acc[mi][ni] = __builtin_amdgcn_mfma_f32_16x16x32_f16(af[mi], bf[ni], acc[mi][ni], 0, 0, 0);
    __syncthreads();
  }
  f16* Qb = Q + b * 1048576 + (long)(g * 256 + m0 + wr * 64) * 1024 + p0 + wc * 64;
#pragma unroll
  for (int mi = 0; mi < 4; ++mi)
#pragma unroll
    for (int q = 0; q < 4; ++q) {
      float bv = bias[g * 256 + m0 + wr * 64 + mi * 16 + (l >> 4) * 4 + q];
#pragma unroll
      for (int ni = 0; ni < 4; ++ni)
        Qb[(long)(mi * 16 + (l >> 4) * 4 + q) * 1024 + ni * 16 + (l & 15)] = (f16)(acc[mi][ni][q] + bv);
    }
}

// ---------------- projection, output transposed [P x C]: Yt[p,c] = sum_i X[i,p] W[o,i] + b[c]
__global__ void __launch_bounds__(256)
proj_kv(const float* __restrict__ X, const f16* __restrict__ W16, const float* __restrict__ bias,
        f16* __restrict__ Yt, int P) {
  __shared__ f16 As[4096], Bs[4096];  // As = Xt [p][i], Bs = W [o][i]
  const int t = threadIdx.x, l = t & 63, w = t >> 6, wr = w >> 1, wc = w & 1;
  const int bg = blockIdx.z, g = bg & 3;
  const long b = bg >> 2;
  const int p0 = blockIdx.y * 128, n0 = blockIdx.x * 128;
  const float* Xb = X + b * 1024 * P + (long)g * 256 * P;
  const f16* Wg = W16 + g * 65536 + n0 * 256;
  const int r0 = t >> 2, cs = (t & 3) ^ ((r0 >> 1) & 3);
  const f16* wS0 = Wg + r0 * 256 + cs * 8;
  const f16* wS1 = Wg + (r0 + 64) * 256 + cs * 8;
  const int xp = t & 63, xc = t >> 6;
  const float* xS = Xb + (long)(xc * 8) * P + p0 + xp;
  const int xo0 = swz(xp, xc), xo1 = swz(xp + 64, xc);
  int offA[4], offB[4];
#pragma unroll
  for (int i = 0; i < 4; ++i) {
    int ra = wr * 64 + i * 16 + (l & 15);
    offA[i] = swz(ra, l >> 4);
    int rb = wc * 64 + i * 16 + (l & 15);
    offB[i] = swz(rb, l >> 4);
  }
  f32x4 acc[4][4] = {};
  for (int k0 = 0; k0 < 256; k0 += 32) {
    gload16(wS0 + k0, Bs + w * 512);
    gload16(wS1 + k0, Bs + 2048 + w * 512);
    const float* xs = xS + (long)k0 * P;
    f16x8 v0, v1;
#pragma unroll
    for (int d = 0; d < 8; ++d) v0[d] = (f16)xs[(long)d * P];
#pragma unroll
    for (int d = 0; d < 8; ++d) v1[d] = (f16)xs[(long)d * P + 64];
    *(f16x8*)((char*)As + xo0) = v0;
    *(f16x8*)((char*)As + xo1) = v1;
    __syncthreads();
    f16x8 af[4], bf[4];
#pragma unroll
    for (int i = 0; i < 4; ++i) {
      af[i] = *(const f16x8*)((const char*)As + offA[i]);
      bf[i] = *(const f16x8*)((const char*)Bs + offB[i]);
    }
#pragma unroll
    for (int mi = 0; mi < 4; ++mi)
#pragma unroll
      for (int ni = 0; ni < 4; ++ni)
        acc[mi][ni] = __builtin_amdgcn_mfma_f32_16x16x32_f16(af[mi], bf[ni], acc[mi][ni], 0, 0, 0);
    __syncthreads();
  }
  f16* Yb = Yt + b * P * 1024 + (long)(p0 + wr * 64) * 1024 + g * 256 + n0 + wc * 64;
  float bcol[4];
#pragma unroll
  for (int ni = 0; ni < 4; ++ni) bcol[ni] = bias[g * 256 + n0 + wc * 64 + ni * 16 + (l & 15)];
#pragma unroll
  for (int mi = 0; mi < 4; ++mi)
#pragma unroll
    for (int q = 0; q < 4; ++q)
#pragma unroll
      for (int ni = 0; ni < 4; ++ni)
        Yb[(long)(mi * 16 + (l >> 4) * 4 + q) * 1024 + ni * 16 + (l & 15)] = (f16)(acc[mi][ni][q] + bcol[ni]);
}

// ---------------- inv[b][j] = 1 / sum_my colsum[b][my][j]   (my: 4 tile-rows of 256)
__global__ void __launch_bounds__(256)
inv_k(const float* __restrict__ colsum, float* __restrict__ inv) {
  int gid = blockIdx.x * 256 + threadIdx.x;  // 8*4096
  int b = gid >> 12, j = gid & 4095;
  const float* cp = colsum + (long)(b * 4) * 4096 + j;
  float s = 0.f;
#pragma unroll
  for (int my = 0; my < 4; ++my) s += cp[my * 4096];
  inv[gid] = 1.f / s;
}

// ---------------- streaming finalize: H f32 = E16*inv -> Hf; E16 <- H16 (in place)
__global__ void __launch_bounds__(256)
h_finalize2(f16* __restrict__ E, float* __restrict__ Hf, const float* __restrict__ inv) {
  for (long g = blockIdx.x * 256L + threadIdx.x; g < 4194304L; g += (long)gridDim.x * 256) {
    long idx8 = g * 8;
    int b = (int)(idx8 >> 22);
    int j = (int)(idx8 & 4095);
    f16x8 e = *(f16x8*)(E + idx8);
    const float* ip = inv + (b << 12) + j;
    f32x4 i0 = *(const f32x4*)ip;
    f32x4 i1 = *(const f32x4*)(ip + 4);
    float h[8];
    f16x8 o;
#pragma unroll
    for (int k = 0; k < 8; ++k) {
      float iv = (k < 4) ? i0[k] : i1[k - 4];
      h[k] = (float)e[k] * iv;
      o[k] = (f16)h[k];
    }
    *(f16x8*)(E + idx8) = o;
    float* hp = Hf + idx8;  // base is only 4B-aligned (out+1 float): scalar stores
#pragma unroll
    for (int k = 0; k < 8; ++k) hp[k] = h[k];
  }
}

__global__ void cvt_f16(const float* __restrict__ s, f16* __restrict__ d, int n) {
  int i = blockIdx.x * 256 + threadIdx.x;
  if (i < n) d[i] = (f16)s[i];
}

__global__ void __launch_bounds__(256)
finalize_k(const float* __restrict__ parts, float* __restrict__ o) {
  const int t = threadIdx.x;
  float s = 0.f;
  for (int i = t; i < 288; i += 256) s += parts[i];
#pragma unroll
  for (int d = 32; d; d >>= 1) s += __shfl_down(s, d);
  __shared__ float red[4];
  if ((t & 63) == 0) red[t >> 6] = s;
  __syncthreads();
  if (t == 0) *o = (red[0] + red[1] + red[2] + red[3]) * (1.0f / 8388608.0f);
}

extern "C" void kernel_launch(void* const* d_in, const int* in_sizes, int n_in,
                              void* d_out, int out_size, void* d_ws, size_t ws_size,
                              hipStream_t stream) {
  const float* Xq = (const float*)d_in[0];
  const float* Xk = (const float*)d_in[1];
  const float* Wq = (const float*)d_in[2];
  const float* bq = (const float*)d_in[3];
  const float* Wk = (const float*)d_in[4];
  const float* bk = (const float*)d_in[5];
  const float* Wv = (const float*)d_in[6];
  const float* bv = (const float*)d_in[7];
  float* out = (float*)d_out;
  float* loss_out = out + 33554432;
  float* Hf = out + 33554433;  // H f32 output [8][1024][4096]

  char* ws = (char*)d_ws;
  f16* W16q = (f16*)(ws);
  f16* W16k = (f16*)(ws + (1 << 19));
  f16* W16v = (f16*)(ws + 2L * (1 << 19));
  f16* Q16  = (f16*)(ws + 3L * (1 << 19));                                  // [8][1024][1024]
  f16* Kt16 = (f16*)(ws + 3L * (1 << 19) + (1L << 24));                     // [8][1024][1024]
  f16* Vt16 = (f16*)(ws + 3L * (1 << 19) + 2L * (1 << 24));                 // [8][4096][1024]
  f16* E16  = (f16*)(ws + 3L * (1 << 19) + 2L * (1 << 24) + (1L << 26));    // [8][1024][4096] -> H16
  f16* E16t = (f16*)(ws + 3L * (1 << 19) + 2L * (1 << 24) + 2L * (1 << 26));// [8][4096][1024]
  float* parts = (float*)(ws + 3L * (1 << 19) + 2L * (1 << 24) + 3L * (1 << 26)); // 288 f32
  float* invb  = (float*)(ws + 3L * (1 << 19) + 2L * (1 << 24) + 3L * (1 << 26) + 8192); // [8][4096]
  // colsum [8][4][4096] f32 = 512KB, overlaps W16q (dead after projections)
  float* colsum = (float*)(ws);

  cvt_f16<<<1024, 256, 0, stream>>>(Wq, W16q, 262144);
  cvt_f16<<<1024, 256, 0, stream>>>(Wk, W16k, 262144);
  cvt_f16<<<1024, 256, 0, stream>>>(Wv, W16v, 262144);

  // Q [C x Pk] natural; K,V transposed [P x C]
  proj_q <<<dim3(8, 2, 32), 256, 0, stream>>>(Xk, W16q, bq, Q16, 1024);
  proj_kv<<<dim3(2, 8, 32), 256, 0, stream>>>(Xk, W16k, bk, Kt16, 1024);
  proj_kv<<<dim3(2, 32, 32), 256, 0, stream>>>(Xq, W16v, bv, Vt16, 4096);

  // E = exp(K^T V /32) -> E16 + E16t (f16) + column partial sums (256^2 tile, counted vmcnt)
  gemm256<2><<<512, 512, 0, stream>>>(Kt16, Vt16, nullptr, E16, E16t,
      1024, 1L << 20, 1L << 22, 0.03125f, colsum);

  inv_k<<<128, 256, 0, stream>>>(colsum, invb);

  // H f32 -> d_out, E16 -> H16 in place
  h_finalize2<<<2048, 256, 0, stream>>>(E16, Hf, invb);

  // out = Q * H = (Q * E^T) * inv[col]
  gemm256<3><<<512, 512, 0, stream>>>(Q16, E16t, out, nullptr, nullptr,
      1024, 1L << 20, 1L << 22, 1.0f, invb);

  // sparse loss: mean((H H^T - I)^2), compact upper triangle (x2 off-diagonal)
  gram_k<<<dim3(36, 1, 8), 256, 0, stream>>>(E16, 4096, 4194304L, parts);
  finalize_k<<<1, 256, 0, stream>>>(parts, loss_out);
}

// Round 5
// 419.424 us; speedup vs baseline: 1.5622x; 1.1167x over previous
//
#include <hip/hip_runtime.h>

typedef _Float16 f16;
typedef f16 f16x8 __attribute__((ext_vector_type(8)));
typedef float f32x4 __attribute__((ext_vector_type(4)));

// async global->LDS, 16B per lane; lds ptr must be wave-uniform base (HW adds lane*16)
__device__ __forceinline__ void gload16(const void* g, void* ldsbase) {
  __builtin_amdgcn_global_load_lds((const __attribute__((address_space(1))) unsigned int*)g,
                                   (__attribute__((address_space(3))) unsigned int*)ldsbase, 16, 0, 0);
}

// swizzled byte offset of 16B chunk c (k-chunk) of row `row` in a [rows][32] f16 tile (BK=32 kernels)
__device__ __forceinline__ int swz(int row, int c) {
  return row * 64 + ((c ^ ((row >> 1) & 3)) << 4);
}

// ================= 256x256 tile, BK=64, 512 threads, counted-vmcnt schedule =================
// NT GEMM: A [M x K], B [N x K] f16, K-contiguous. M=1024 (by: 4), N=4096 (bx: 16), batch 8.
// MODE 2: E = exp(A*B^T * scale) -> E16 [M x N] + E16t [N x M] + column partial sums (aux)
// MODE 3: C = (A*B^T) * aux[col]  (f32)
template<int MODE>
__global__ void __launch_bounds__(512, 2)
gemm256(const f16* __restrict__ A, const f16* __restrict__ Bm, float* __restrict__ Cf,
        f16* __restrict__ E16, f16* __restrict__ E16t,
        int K, long sA, long sB, float scale, float* __restrict__ aux) {
  __shared__ f16 sb[65536];  // 128 KB: A0[16384] B0[16384] A1[16384] B1[16384]
  const int t = threadIdx.x, l = t & 63, w = t >> 6;
  const int wr = w >> 2, wc = w & 3;
  const int bid = blockIdx.x;
  const int swzb = (bid & 7) * 64 + (bid >> 3);  // XCD-chunked (512 % 8 == 0)
  const long b = swzb >> 6;
  const int by = (swzb >> 4) & 3, bx = swzb & 15;
  const char* Abyte = (const char*)(A + b * sA + (long)(by * 256) * K);
  const char* Bbyte = (const char*)(Bm + b * sB + (long)(bx * 256) * K);

  // staging source byte-offsets (pre-swizzled source, linear LDS dest)
  int offSrc[4];
#pragma unroll
  for (int i = 0; i < 4; ++i) {
    int cid = i * 512 + t, row = cid >> 3, slot = cid & 7;
    offSrc[i] = row * (K * 2) + ((slot ^ (row & 7)) << 4);
  }
  // fragment element-offsets in the [256][64] swizzled tile
  int offAf[8][2], offBf[4][2];
#pragma unroll
  for (int mi = 0; mi < 8; ++mi) {
    int r = wr * 128 + mi * 16 + (l & 15);
#pragma unroll
    for (int ks = 0; ks < 2; ++ks)
      offAf[mi][ks] = r * 64 + ((((ks << 2) + (l >> 4)) ^ (r & 7)) << 3);
  }
#pragma unroll
  for (int ni = 0; ni < 4; ++ni) {
    int r = wc * 64 + ni * 16 + (l & 15);
#pragma unroll
    for (int ks = 0; ks < 2; ++ks)
      offBf[ni][ks] = r * 64 + ((((ks << 2) + (l >> 4)) ^ (r & 7)) << 3);
  }

  const int NT = K >> 6;
  f32x4 acc[8][4] = {};

  auto STAGE = [&](int kt, int bsel) {
    f16* la = sb + bsel * 32768;
    f16* lb = la + 16384;
    const char* as = Abyte + (long)kt * 128;
    const char* bs = Bbyte + (long)kt * 128;
#pragma unroll
    for (int i = 0; i < 4; ++i)
      gload16(as + offSrc[i], la + (i * 512 + (w << 6)) * 8);
#pragma unroll
    for (int i = 0; i < 4; ++i)
      gload16(bs + offSrc[i], lb + (i * 512 + (w << 6)) * 8);
  };

  STAGE(0, 0);
  for (int kt = 0; kt < NT; ++kt) {
    const int cur = kt & 1;
    if (kt + 1 < NT) {
      STAGE(kt + 1, cur ^ 1);
      asm volatile("s_waitcnt vmcnt(8)" ::: "memory");  // kt's 8 loads done; kt+1's 8 in flight
    } else {
      asm volatile("s_waitcnt vmcnt(0)" ::: "memory");
    }
    __builtin_amdgcn_s_barrier();
    asm volatile("" ::: "memory");
    const f16* la = sb + cur * 32768;
    const f16* lb = la + 16384;
#pragma unroll
    for (int ks = 0; ks < 2; ++ks) {
      f16x8 bf[4];
#pragma unroll
      for (int ni = 0; ni < 4; ++ni) bf[ni] = *(const f16x8*)(lb + offBf[ni][ks]);
#pragma unroll
      for (int mi = 0; mi < 8; ++mi) {
        f16x8 af = *(const f16x8*)(la + offAf[mi][ks]);
#pragma unroll
        for (int ni = 0; ni < 4; ++ni)
          acc[mi][ni] = __builtin_amdgcn_mfma_f32_16x16x32_f16(af, bf[ni], acc[mi][ni], 0, 0, 0);
      }
    }
    asm volatile("s_waitcnt lgkmcnt(0)" ::: "memory");
    __builtin_amdgcn_s_barrier();
    asm volatile("" ::: "memory");
  }

  const int i0 = by * 256, j0 = bx * 256;
  if (MODE == 2) {
    float csum[4] = {};
#pragma unroll
    for (int mi = 0; mi < 8; ++mi)
#pragma unroll
      for (int ni = 0; ni < 4; ++ni)
#pragma unroll
        for (int q = 0; q < 4; ++q) {
          float e = __expf(acc[mi][ni][q] * scale);
          acc[mi][ni][q] = e;
          csum[ni] += e;
        }
#pragma unroll
    for (int ni = 0; ni < 4; ++ni) {
      csum[ni] += __shfl_xor(csum[ni], 16);
      csum[ni] += __shfl_xor(csum[ni], 32);
    }
    float* colp = (float*)(sb + 34816);  // past the 64x264 slab region
    if (l < 16) {
#pragma unroll
      for (int ni = 0; ni < 4; ++ni) colp[wr * 256 + wc * 64 + ni * 16 + l] = csum[ni];
    }
    __syncthreads();
    if (t < 256) aux[(b * 4 + by) * 4096 + bx * 256 + t] = colp[t] + colp[256 + t];
    f16* E16b = E16 + b * 4194304L;
    f16* E16tb = E16t + b * 4194304L;
#pragma unroll
    for (int s = 0; s < 4; ++s) {
      if (wr == (s >> 1)) {  // slab s = rows [s*64, s*64+64) of the tile, padded stride 264
        const int h = s & 1;
#pragma unroll
        for (int m2 = 0; m2 < 4; ++m2)
#pragma unroll
          for (int ni = 0; ni < 4; ++ni)
#pragma unroll
            for (int q = 0; q < 4; ++q)
              sb[(m2 * 16 + (l >> 4) * 4 + q) * 264 + wc * 64 + ni * 16 + (l & 15)] =
                  (f16)acc[h * 4 + m2][ni][q];
      }
      __syncthreads();
#pragma unroll
      for (int ii = 0; ii < 4; ++ii) {  // E16 row-major readout, coalesced 16B
        int cid = ii * 512 + t, r = cid >> 5, cc = cid & 31;
        *(f16x8*)(E16b + (long)(i0 + s * 64 + r) * 4096 + j0 + cc * 8) =
            *(const f16x8*)(sb + r * 264 + cc * 8);
      }
      const int q4 = w >> 1, r8 = l >> 3, ic = l & 7;
#pragma unroll
      for (int ii = 0; ii < 4; ++ii) {  // E16t: column gather (bank-balanced), 16B stores
        int j = q4 * 64 + r8 * 8 + (w & 1) * 4 + ii;
        f16x8 v;
#pragma unroll
        for (int k2 = 0; k2 < 8; ++k2) v[k2] = sb[(ic * 8 + k2) * 264 + j];
        *(f16x8*)(E16tb + (long)(j0 + j) * 1024 + i0 + s * 64 + ic * 8) = v;
      }
      __syncthreads();
    }
  } else {  // MODE 3
    const float* ip = aux + b * 4096 + bx * 256 + wc * 64;
    float iv[4];
#pragma unroll
    for (int ni = 0; ni < 4; ++ni) iv[ni] = ip[ni * 16 + (l & 15)];
    float* Cb = Cf + b * 4194304L + (long)(by * 256 + wr * 128) * 4096 + bx * 256 + wc * 64;
#pragma unroll
    for (int mi = 0; mi < 8; ++mi)
#pragma unroll
      for (int ni = 0; ni < 4; ++ni)
#pragma unroll
        for (int q = 0; q < 4; ++q)
          Cb[(long)(mi * 16 + (l >> 4) * 4 + q) * 4096 + ni * 16 + (l & 15)] = acc[mi][ni][q] * iv[ni];
  }
}

// ================= Gram loss: 128x128 tile, BK=64, counted vmcnt, inv-scaled fragments ========
// mid[c,k] = sum_j (E[c,j]*inv[j]) * (E[k,j]*inv[j]);  partial loss per block -> parts[bid]
// grid: 512 blocks = 8 batches x (8x8 tiles), 256 threads, 72KB LDS -> 2 blocks/CU
__global__ void __launch_bounds__(256, 2)
gram_p(const f16* __restrict__ E, const f16* __restrict__ inv16g, float* __restrict__ parts) {
  __shared__ f16 sb[36864];  // A0[8192] B0[8192] A1[8192] B1[8192] inv[4096]
  const int t = threadIdx.x, l = t & 63, w = t >> 6, wr = w >> 1, wc = w & 1;
  const int bid = blockIdx.x;
  const int swzb = (bid & 7) * 64 + (bid >> 3);  // XCD-chunked: each XCD owns one batch
  const long b = swzb >> 6;
  const int by = (swzb >> 3) & 7, bx = swzb & 7;
  const char* Abyte = (const char*)(E + b * 4194304L + (long)(by * 128) * 4096);
  const char* Bbyte = (const char*)(E + b * 4194304L + (long)(bx * 128) * 4096);
  f16* invl = sb + 32768;
  {  // stage inv16 [4096] f16 = 8KB via 2 gload rounds (counts in prologue vmcnt)
    const char* ig = (const char*)(inv16g + b * 4096);
    gload16(ig + (long)t * 16, invl + (w << 6) * 8);
    gload16(ig + 4096 + (long)t * 16, invl + 2048 + (w << 6) * 8);
  }
  int offSrc[4];
#pragma unroll
  for (int i = 0; i < 4; ++i) {
    int cid = i * 256 + t, row = cid >> 3, slot = cid & 7;
    offSrc[i] = row * 8192 + ((slot ^ (row & 7)) << 4);  // row stride = 4096 f16 = 8192 B
  }
  int offA[4][2], offB[4][2];
#pragma unroll
  for (int mi = 0; mi < 4; ++mi) {
    int ra = wr * 64 + mi * 16 + (l & 15);
    int rb = wc * 64 + mi * 16 + (l & 15);
#pragma unroll
    for (int ks = 0; ks < 2; ++ks) {
      offA[mi][ks] = ra * 64 + ((((ks << 2) + (l >> 4)) ^ (ra & 7)) << 3);
      offB[mi][ks] = rb * 64 + ((((ks << 2) + (l >> 4)) ^ (rb & 7)) << 3);
    }
  }
  auto STAGE = [&](int kt, int bsel) {
    f16* la = sb + bsel * 16384;
    f16* lb = la + 8192;
    const char* as = Abyte + (long)kt * 128;
    const char* bs = Bbyte + (long)kt * 128;
#pragma unroll
    for (int i = 0; i < 4; ++i) gload16(as + offSrc[i], la + (i * 256 + (w << 6)) * 8);
#pragma unroll
    for (int i = 0; i < 4; ++i) gload16(bs + offSrc[i], lb + (i * 256 + (w << 6)) * 8);
  };
  f32x4 acc[4][4] = {};
  STAGE(0, 0);
  for (int kt = 0; kt < 64; ++kt) {
    const int cur = kt & 1;
    if (kt + 1 < 64) {
      STAGE(kt + 1, cur ^ 1);
      asm volatile("s_waitcnt vmcnt(8)" ::: "memory");
    } else {
      asm volatile("s_waitcnt vmcnt(0)" ::: "memory");
    }
    __builtin_amdgcn_s_barrier();
    asm volatile("" ::: "memory");
    const f16* la = sb + cur * 16384;
    const f16* lb = la + 8192;
#pragma unroll
    for (int ks = 0; ks < 2; ++ks) {
      const f16x8 invv = *(const f16x8*)(invl + kt * 64 + ks * 32 + ((l >> 4) << 3));
      f16x8 bf[4];
#pragma unroll
      for (int ni = 0; ni < 4; ++ni) bf[ni] = *(const f16x8*)(lb + offB[ni][ks]) * invv;
#pragma unroll
      for (int mi = 0; mi < 4; ++mi) {
        f16x8 af = *(const f16x8*)(la + offA[mi][ks]) * invv;
#pragma unroll
        for (int ni = 0; ni < 4; ++ni)
          acc[mi][ni] = __builtin_amdgcn_mfma_f32_16x16x32_f16(af, bf[ni], acc[mi][ni], 0, 0, 0);
      }
    }
    asm volatile("s_waitcnt lgkmcnt(0)" ::: "memory");
    __builtin_amdgcn_s_barrier();
    asm volatile("" ::: "memory");
  }
  const int gr0 = by * 128 + wr * 64 + (l >> 4) * 4;
  const int gc0 = bx * 128 + wc * 64 + (l & 15);
  float p = 0.f;
#pragma unroll
  for (int mi = 0; mi < 4; ++mi)
#pragma unroll
    for (int ni = 0; ni < 4; ++ni)
#pragma unroll
      for (int q = 0; q < 4; ++q) {
        float e = acc[mi][ni][q];
        if (gr0 + mi * 16 + q == gc0 + ni * 16) e -= 1.f;
        p += e * e;
      }
#pragma unroll
  for (int d = 32; d; d >>= 1) p += __shfl_down(p, d);
  __shared__ float red[4];
  if (l == 0) red[w] = p;
  __syncthreads();
  if (t == 0) parts[bid] = red[0] + red[1] + red[2] + red[3];
}

// ---------------- projection, output natural [C x P]: Q[o,p] = sum_i W[o,i] X[i,p] + b[o]
__global__ void __launch_bounds__(256)
proj_q(const float* __restrict__ X, const f16* __restrict__ W16, const float* __restrict__ bias,
       f16* __restrict__ Q, int P) {
  __shared__ f16 As[4096], Bs[4096];  // As = W [o][i], Bs = Xt [p][i]
  const int t = threadIdx.x, l = t & 63, w = t >> 6, wr = w >> 1, wc = w & 1;
  const int bg = blockIdx.z, g = bg & 3;
  const long b = bg >> 2;
  const int p0 = blockIdx.x * 128, m0 = blockIdx.y * 128;
  const float* Xb = X + b * 1024 * P + (long)g * 256 * P;
  const f16* Wg = W16 + g * 65536 + m0 * 256;
  const int r0 = t >> 2, cs = (t & 3) ^ ((r0 >> 1) & 3);
  const f16* wS0 = Wg + r0 * 256 + cs * 8;
  const f16* wS1 = Wg + (r0 + 64) * 256 + cs * 8;
  const int xp = t & 63, xc = t >> 6;
  const float* xS = Xb + (long)(xc * 8) * P + p0 + xp;
  const int xo0 = swz(xp, xc), xo1 = swz(xp + 64, xc);
  int offA[4], offB[4];
#pragma unroll
  for (int i = 0; i < 4; ++i) {
    int ra = wr * 64 + i * 16 + (l & 15);
    offA[i] = swz(ra, l >> 4);
    int rb = wc * 64 + i * 16 + (l & 15);
    offB[i] = swz(rb, l >> 4);
  }
  f32x4 acc[4][4] = {};
  for (int k0 = 0; k0 < 256; k0 += 32) {
    gload16(wS0 + k0, As + w * 512);
    gload16(wS1 + k0, As + 2048 + w * 512);
    const float* xs = xS + (long)k0 * P;
    f16x8 v0, v1;
#pragma unroll
    for (int d = 0; d < 8; ++d) v0[d] = (f16)xs[(long)d * P];
#pragma unroll
    for (int d = 0; d < 8; ++d) v1[d] = (f16)xs[(long)d * P + 64];
    *(f16x8*)((char*)Bs + xo0) = v0;
    *(f16x8*)((char*)Bs + xo1) = v1;
    __syncthreads();
    f16x8 af[4], bf[4];
#pragma unroll
    for (int i = 0; i < 4; ++i) {
      af[i] = *(const f16x8*)((const char*)As + offA[i]);
      bf[i] = *(const f16x8*)((const char*)Bs + offB[i]);
    }
#pragma unroll
    for (int mi = 0; mi < 4; ++mi)
#pragma unroll
      for (int ni = 0; ni < 4; ++ni)
        acc[mi][ni] = __builtin_amdgcn_mfma_f32_16x16x32_f16(af[mi], bf[ni], acc[mi][ni], 0, 0, 0);
    __syncthreads();
  }
  f16* Qb = Q + b * 1048576 + (long)(g * 256 + m0 + wr * 64) * 1024 + p0 + wc * 64;
#pragma unroll
  for (int mi = 0; mi < 4; ++mi)
#pragma unroll
    for (int q = 0; q < 4; ++q) {
      float bv = bias[g * 256 + m0 + wr * 64 + mi * 16 + (l >> 4) * 4 + q];
#pragma unroll
      for (int ni = 0; ni < 4; ++ni)
        Qb[(long)(mi * 16 + (l >> 4) * 4 + q) * 1024 + ni * 16 + (l & 15)] = (f16)(acc[mi][ni][q] + bv);
    }
}

// ---------------- projection, output transposed [P x C]: Yt[p,c] = sum_i X[i,p] W[o,i] + b[c]
__global__ void __launch_bounds__(256)
proj_kv(const float* __restrict__ X, const f16* __restrict__ W16, const float* __restrict__ bias,
        f16* __restrict__ Yt, int P) {
  __shared__ f16 As[4096], Bs[4096];  // As = Xt [p][i], Bs = W [o][i]
  const int t = threadIdx.x, l = t & 63, w = t >> 6, wr = w >> 1, wc = w & 1;
  const int bg = blockIdx.z, g = bg & 3;
  const long b = bg >> 2;
  const int p0 = blockIdx.y * 128, n0 = blockIdx.x * 128;
  const float* Xb = X + b * 1024 * P + (long)g * 256 * P;
  const f16* Wg = W16 + g * 65536 + n0 * 256;
  const int r0 = t >> 2, cs = (t & 3) ^ ((r0 >> 1) & 3);
  const f16* wS0 = Wg + r0 * 256 + cs * 8;
  const f16* wS1 = Wg + (r0 + 64) * 256 + cs * 8;
  const int xp = t & 63, xc = t >> 6;
  const float* xS = Xb + (long)(xc * 8) * P + p0 + xp;
  const int xo0 = swz(xp, xc), xo1 = swz(xp + 64, xc);
  int offA[4], offB[4];
#pragma unroll
  for (int i = 0; i < 4; ++i) {
    int ra = wr * 64 + i * 16 + (l & 15);
    offA[i] = swz(ra, l >> 4);
    int rb = wc * 64 + i * 16 + (l & 15);
    offB[i] = swz(rb, l >> 4);
  }
  f32x4 acc[4][4] = {};
  for (int k0 = 0; k0 < 256; k0 += 32) {
    gload16(wS0 + k0, Bs + w * 512);
    gload16(wS1 + k0, Bs + 2048 + w * 512);
    const float* xs = xS + (long)k0 * P;
    f16x8 v0, v1;
#pragma unroll
    for (int d = 0; d < 8; ++d) v0[d] = (f16)xs[(long)d * P];
#pragma unroll
    for (int d = 0; d < 8; ++d) v1[d] = (f16)xs[(long)d * P + 64];
    *(f16x8*)((char*)As + xo0) = v0;
    *(f16x8*)((char*)As + xo1) = v1;
    __syncthreads();
    f16x8 af[4], bf[4];
#pragma unroll
    for (int i = 0; i < 4; ++i) {
      af[i] = *(const f16x8*)((const char*)As + offA[i]);
      bf[i] = *(const f16x8*)((const char*)Bs + offB[i]);
    }
#pragma unroll
    for (int mi = 0; mi < 4; ++mi)
#pragma unroll
      for (int ni = 0; ni < 4; ++ni)
        acc[mi][ni] = __builtin_amdgcn_mfma_f32_16x16x32_f16(af[mi], bf[ni], acc[mi][ni], 0, 0, 0);
    __syncthreads();
  }
  f16* Yb = Yt + b * P * 1024 + (long)(p0 + wr * 64) * 1024 + g * 256 + n0 + wc * 64;
  float bcol[4];
#pragma unroll
  for (int ni = 0; ni < 4; ++ni) bcol[ni] = bias[g * 256 + n0 + wc * 64 + ni * 16 + (l & 15)];
#pragma unroll
  for (int mi = 0; mi < 4; ++mi)
#pragma unroll
    for (int q = 0; q < 4; ++q)
#pragma unroll
      for (int ni = 0; ni < 4; ++ni)
        Yb[(long)(mi * 16 + (l >> 4) * 4 + q) * 1024 + ni * 16 + (l & 15)] = (f16)(acc[mi][ni][q] + bcol[ni]);
}

// ---------------- inv[b][j] = 1 / sum_my colsum[b][my][j]   (my: 4 tile-rows of 256)
__global__ void __launch_bounds__(256)
inv_k(const float* __restrict__ colsum, float* __restrict__ inv, f16* __restrict__ inv16) {
  int gid = blockIdx.x * 256 + threadIdx.x;  // 8*4096
  int b = gid >> 12, j = gid & 4095;
  const float* cp = colsum + (long)(b * 4) * 4096 + j;
  float s = 0.f;
#pragma unroll
  for (int my = 0; my < 4; ++my) s += cp[my * 4096];
  float iv = 1.f / s;
  inv[gid] = iv;
  inv16[gid] = (f16)iv;
}

// ---------------- streaming finalize: Hf f32 = E16*inv (fully per-instruction coalesced)
__global__ void __launch_bounds__(256)
h_fin(const f16* __restrict__ E, float* __restrict__ Hf, const float* __restrict__ inv) {
  for (long g = blockIdx.x * 256L + threadIdx.x; g < 33554432L; g += (long)gridDim.x * 256) {
    int b = (int)(g >> 22), j = (int)(g & 4095);
    Hf[g] = (float)E[g] * inv[(b << 12) + j];
  }
}

__global__ void cvt_f16(const float* __restrict__ s, f16* __restrict__ d, int n) {
  int i = blockIdx.x * 256 + threadIdx.x;
  if (i < n) d[i] = (f16)s[i];
}

__global__ void __launch_bounds__(256)
finalize_k(const float* __restrict__ parts, float* __restrict__ o) {
  const int t = threadIdx.x;
  float s = 0.f;
  for (int i = t; i < 512; i += 256) s += parts[i];
#pragma unroll
  for (int d = 32; d; d >>= 1) s += __shfl_down(s, d);
  __shared__ float red[4];
  if ((t & 63) == 0) red[t >> 6] = s;
  __syncthreads();
  if (t == 0) *o = (red[0] + red[1] + red[2] + red[3]) * (1.0f / 8388608.0f);
}

extern "C" void kernel_launch(void* const* d_in, const int* in_sizes, int n_in,
                              void* d_out, int out_size, void* d_ws, size_t ws_size,
                              hipStream_t stream) {
  const float* Xq = (const float*)d_in[0];
  const float* Xk = (const float*)d_in[1];
  const float* Wq = (const float*)d_in[2];
  const float* bq = (const float*)d_in[3];
  const float* Wk = (const float*)d_in[4];
  const float* bk = (const float*)d_in[5];
  const float* Wv = (const float*)d_in[6];
  const float* bv = (const float*)d_in[7];
  float* out = (float*)d_out;
  float* loss_out = out + 33554432;
  float* Hf = out + 33554433;  // H f32 output [8][1024][4096]

  char* ws = (char*)d_ws;
  f16* W16q = (f16*)(ws);
  f16* W16k = (f16*)(ws + (1 << 19));
  f16* W16v = (f16*)(ws + 2L * (1 << 19));
  f16* Q16  = (f16*)(ws + 3L * (1 << 19));                                  // [8][1024][1024]
  f16* Kt16 = (f16*)(ws + 3L * (1 << 19) + (1L << 24));                     // [8][1024][1024]
  f16* Vt16 = (f16*)(ws + 3L * (1 << 19) + 2L * (1 << 24));                 // [8][4096][1024]
  f16* E16  = (f16*)(ws + 3L * (1 << 19) + 2L * (1 << 24) + (1L << 26));    // [8][1024][4096]
  f16* E16t = (f16*)(ws + 3L * (1 << 19) + 2L * (1 << 24) + 2L * (1 << 26));// [8][4096][1024]
  char* tail = ws + 3L * (1 << 19) + 2L * (1 << 24) + 3L * (1 << 26);
  float* parts = (float*)tail;                 // 512 f32
  float* invb  = (float*)(tail + 8192);        // [8][4096] f32
  f16*   inv16 = (f16*)(tail + 8192 + 131072); // [8][4096] f16
  // colsum [8][4][4096] f32 = 512KB, overlaps W16q (dead after projections)
  float* colsum = (float*)(ws);

  cvt_f16<<<1024, 256, 0, stream>>>(Wq, W16q, 262144);
  cvt_f16<<<1024, 256, 0, stream>>>(Wk, W16k, 262144);
  cvt_f16<<<1024, 256, 0, stream>>>(Wv, W16v, 262144);

  // Q [C x Pk] natural; K,V transposed [P x C]
  proj_q <<<dim3(8, 2, 32), 256, 0, stream>>>(Xk, W16q, bq, Q16, 1024);
  proj_kv<<<dim3(2, 8, 32), 256, 0, stream>>>(Xk, W16k, bk, Kt16, 1024);
  proj_kv<<<dim3(2, 32, 32), 256, 0, stream>>>(Xq, W16v, bv, Vt16, 4096);

  // E = exp(K^T V /32) -> E16 + E16t (f16) + column partial sums (256^2 tile, counted vmcnt)
  gemm256<2><<<512, 512, 0, stream>>>(Kt16, Vt16, nullptr, E16, E16t,
      1024, 1L << 20, 1L << 22, 0.03125f, colsum);

  inv_k<<<128, 256, 0, stream>>>(colsum, invb, inv16);

  // out = Q * H = (Q * E^T) * inv[col]
  gemm256<3><<<512, 512, 0, stream>>>(Q16, E16t, out, nullptr, nullptr,
      1024, 1L << 20, 1L << 22, 1.0f, invb);

  // H f32 -> d_out (streaming)
  h_fin<<<2048, 256, 0, stream>>>(E16, Hf, invb);

  // sparse loss: mean((H H^T - I)^2), H = E*inv fused in-fragment
  gram_p<<<512, 256, 0, stream>>>(E16, inv16, parts);
  finalize_k<<<1, 256, 0, stream>>>(parts, loss_out);
}

// Round 6
// 385.075 us; speedup vs baseline: 1.7015x; 1.0892x over previous
//
#include <hip/hip_runtime.h>

typedef _Float16 f16;
typedef f16 f16x4 __attribute__((ext_vector_type(4)));
typedef f16 f16x8 __attribute__((ext_vector_type(8)));
typedef float f32x4 __attribute__((ext_vector_type(4)));

// async global->LDS, 16B per lane; lds ptr must be wave-uniform base (HW adds lane*16)
__device__ __forceinline__ void gload16(const void* g, void* ldsbase) {
  __builtin_amdgcn_global_load_lds((const __attribute__((address_space(1))) unsigned int*)g,
                                   (__attribute__((address_space(3))) unsigned int*)ldsbase, 16, 0, 0);
}

// swizzled byte offset of 16B chunk c (k-chunk) of row `row` in a [rows][32] f16 tile (BK=32 kernels)
__device__ __forceinline__ int swz(int row, int c) {
  return row * 64 + ((c ^ ((row >> 1) & 3)) << 4);
}

// ================= 256x256 tile, BK=64, 512 threads, counted-vmcnt schedule =================
// NT GEMM: A [M x K], B [N x K] f16, K-contiguous. M=1024 (by: 4), N=4096 (bx: 16), batch 8.
// MODE 2: E = exp(A*B^T * scale) -> E16 [M x N] + E16t [N x M] + column partial sums (aux)
// MODE 3: C = (A*B^T) * aux[col]  (f32)
template<int MODE>
__global__ void __launch_bounds__(512, 2)
gemm256(const f16* __restrict__ A, const f16* __restrict__ Bm, float* __restrict__ Cf,
        f16* __restrict__ E16, f16* __restrict__ E16t,
        int K, long sA, long sB, float scale, float* __restrict__ aux) {
  __shared__ f16 sb[65536];  // 128 KB: A0[16384] B0[16384] A1[16384] B1[16384]
  const int t = threadIdx.x, l = t & 63, w = t >> 6;
  const int wr = w >> 2, wc = w & 3;
  const int bid = blockIdx.x;
  const int swzb = (bid & 7) * 64 + (bid >> 3);  // XCD-chunked (512 % 8 == 0)
  const long b = swzb >> 6;
  const int inner = swzb & 63;
  const int bx = inner >> 2, by = inner & 3;  // by fastest: 4 consecutive blocks share B-panel in L2
  const char* Abyte = (const char*)(A + b * sA + (long)(by * 256) * K);
  const char* Bbyte = (const char*)(Bm + b * sB + (long)(bx * 256) * K);

  // staging source byte-offsets (pre-swizzled source, linear LDS dest)
  int offSrc[4];
#pragma unroll
  for (int i = 0; i < 4; ++i) {
    int cid = i * 512 + t, row = cid >> 3, slot = cid & 7;
    offSrc[i] = row * (K * 2) + ((slot ^ (row & 7)) << 4);
  }
  // fragment element-offsets in the [256][64] swizzled tile
  int offAf[8][2], offBf[4][2];
#pragma unroll
  for (int mi = 0; mi < 8; ++mi) {
    int r = wr * 128 + mi * 16 + (l & 15);
#pragma unroll
    for (int ks = 0; ks < 2; ++ks)
      offAf[mi][ks] = r * 64 + ((((ks << 2) + (l >> 4)) ^ (r & 7)) << 3);
  }
#pragma unroll
  for (int ni = 0; ni < 4; ++ni) {
    int r = wc * 64 + ni * 16 + (l & 15);
#pragma unroll
    for (int ks = 0; ks < 2; ++ks)
      offBf[ni][ks] = r * 64 + ((((ks << 2) + (l >> 4)) ^ (r & 7)) << 3);
  }

  const int NT = K >> 6;
  f32x4 acc[8][4] = {};

  auto STAGE = [&](int kt, int bsel) {
    f16* la = sb + bsel * 32768;
    f16* lb = la + 16384;
    const char* as = Abyte + (long)kt * 128;
    const char* bs = Bbyte + (long)kt * 128;
#pragma unroll
    for (int i = 0; i < 4; ++i)
      gload16(as + offSrc[i], la + (i * 512 + (w << 6)) * 8);
#pragma unroll
    for (int i = 0; i < 4; ++i)
      gload16(bs + offSrc[i], lb + (i * 512 + (w << 6)) * 8);
  };

  STAGE(0, 0);
  for (int kt = 0; kt < NT; ++kt) {
    const int cur = kt & 1;
    if (kt + 1 < NT) {
      STAGE(kt + 1, cur ^ 1);
      asm volatile("s_waitcnt vmcnt(8)" ::: "memory");  // kt's 8 loads done; kt+1's 8 in flight
    } else {
      asm volatile("s_waitcnt vmcnt(0)" ::: "memory");
    }
    __builtin_amdgcn_s_barrier();
    asm volatile("" ::: "memory");
    const f16* la = sb + cur * 32768;
    const f16* lb = la + 16384;
#pragma unroll
    for (int ks = 0; ks < 2; ++ks) {
      f16x8 bf[4];
#pragma unroll
      for (int ni = 0; ni < 4; ++ni) bf[ni] = *(const f16x8*)(lb + offBf[ni][ks]);
#pragma unroll
      for (int mi = 0; mi < 8; ++mi) {
        f16x8 af = *(const f16x8*)(la + offAf[mi][ks]);
#pragma unroll
        for (int ni = 0; ni < 4; ++ni)
          acc[mi][ni] = __builtin_amdgcn_mfma_f32_16x16x32_f16(af, bf[ni], acc[mi][ni], 0, 0, 0);
      }
    }
    asm volatile("s_waitcnt lgkmcnt(0)" ::: "memory");
    __builtin_amdgcn_s_barrier();
    asm volatile("" ::: "memory");
  }

  const int i0 = by * 256, j0 = bx * 256;
  if (MODE == 2) {
    float csum[4] = {};
#pragma unroll
    for (int mi = 0; mi < 8; ++mi)
#pragma unroll
      for (int ni = 0; ni < 4; ++ni)
#pragma unroll
        for (int q = 0; q < 4; ++q) {
          float e = __expf(acc[mi][ni][q] * scale);
          acc[mi][ni][q] = e;
          csum[ni] += e;
        }
#pragma unroll
    for (int ni = 0; ni < 4; ++ni) {
      csum[ni] += __shfl_xor(csum[ni], 16);
      csum[ni] += __shfl_xor(csum[ni], 32);
    }
    float* colp = (float*)(sb + 34816);  // past the 64x264 slab region
    if (l < 16) {
#pragma unroll
      for (int ni = 0; ni < 4; ++ni) colp[wr * 256 + wc * 64 + ni * 16 + l] = csum[ni];
    }
    __syncthreads();
    if (t < 256) aux[(b * 4 + by) * 4096 + bx * 256 + t] = colp[t] + colp[256 + t];
    f16* E16b = E16 + b * 4194304L;
    f16* E16tb = E16t + b * 4194304L;
#pragma unroll
    for (int s = 0; s < 4; ++s) {
      if (wr == (s >> 1)) {  // slab s = rows [s*64, s*64+64) of the tile, padded stride 264
        const int h = s & 1;
#pragma unroll
        for (int m2 = 0; m2 < 4; ++m2)
#pragma unroll
          for (int ni = 0; ni < 4; ++ni)
#pragma unroll
            for (int q = 0; q < 4; ++q)
              sb[(m2 * 16 + (l >> 4) * 4 + q) * 264 + wc * 64 + ni * 16 + (l & 15)] =
                  (f16)acc[h * 4 + m2][ni][q];
      }
      __syncthreads();
#pragma unroll
      for (int ii = 0; ii < 4; ++ii) {  // E16 row-major readout, coalesced 16B
        int cid = ii * 512 + t, r = cid >> 5, cc = cid & 31;
        *(f16x8*)(E16b + (long)(i0 + s * 64 + r) * 4096 + j0 + cc * 8) =
            *(const f16x8*)(sb + r * 264 + cc * 8);
      }
      const int q4 = w >> 1, r8 = l >> 3, ic = l & 7;
#pragma unroll
      for (int ii = 0; ii < 4; ++ii) {  // E16t: column gather (bank-balanced), 16B stores
        int j = q4 * 64 + r8 * 8 + (w & 1) * 4 + ii;
        f16x8 v;
#pragma unroll
        for (int k2 = 0; k2 < 8; ++k2) v[k2] = sb[(ic * 8 + k2) * 264 + j];
        *(f16x8*)(E16tb + (long)(j0 + j) * 1024 + i0 + s * 64 + ic * 8) = v;
      }
      __syncthreads();
    }
  } else {  // MODE 3
    const float* ip = aux + b * 4096 + bx * 256 + wc * 64;
    float iv[4];
#pragma unroll
    for (int ni = 0; ni < 4; ++ni) iv[ni] = ip[ni * 16 + (l & 15)];
    float* Cb = Cf + b * 4194304L + (long)(by * 256 + wr * 128) * 4096 + bx * 256 + wc * 64;
#pragma unroll
    for (int mi = 0; mi < 8; ++mi)
#pragma unroll
      for (int ni = 0; ni < 4; ++ni)
#pragma unroll
        for (int q = 0; q < 4; ++q)
          Cb[(long)(mi * 16 + (l >> 4) * 4 + q) * 4096 + ni * 16 + (l & 15)] = acc[mi][ni][q] * iv[ni];
  }
}

// ================= Gram loss: 128x128 tile, BK=64, counted vmcnt ==============================
// mid[c,k]*4096 = sum_j (E[c,j]*inv2s[j]) * E[k,j],  inv2s = inv^2*4096 (A-side-only scaling)
// grid: 512 blocks = 8 batches x (8x8 tiles), 256 threads, 72KB LDS -> 2 blocks/CU
__global__ void __launch_bounds__(256, 2)
gram_p(const f16* __restrict__ E, const f16* __restrict__ inv2sg, float* __restrict__ parts) {
  __shared__ f16 sb[36864];  // A0[8192] B0[8192] A1[8192] B1[8192] inv[4096]
  const int t = threadIdx.x, l = t & 63, w = t >> 6, wr = w >> 1, wc = w & 1;
  const int bid = blockIdx.x;
  const int swzb = (bid & 7) * 64 + (bid >> 3);  // XCD-chunked: each XCD owns one batch
  const long b = swzb >> 6;
  const int by = (swzb >> 3) & 7, bx = swzb & 7;
  const char* Abyte = (const char*)(E + b * 4194304L + (long)(by * 128) * 4096);
  const char* Bbyte = (const char*)(E + b * 4194304L + (long)(bx * 128) * 4096);
  f16* invl = sb + 32768;
  {  // stage inv2s [4096] f16 = 8KB via 2 gload rounds (counts in prologue vmcnt)
    const char* ig = (const char*)(inv2sg + b * 4096);
    gload16(ig + (long)t * 16, invl + (w << 6) * 8);
    gload16(ig + 4096 + (long)t * 16, invl + 2048 + (w << 6) * 8);
  }
  int offSrc[4];
#pragma unroll
  for (int i = 0; i < 4; ++i) {
    int cid = i * 256 + t, row = cid >> 3, slot = cid & 7;
    offSrc[i] = row * 8192 + ((slot ^ (row & 7)) << 4);  // row stride = 4096 f16 = 8192 B
  }
  int offA[4][2], offB[4][2];
#pragma unroll
  for (int mi = 0; mi < 4; ++mi) {
    int ra = wr * 64 + mi * 16 + (l & 15);
    int rb = wc * 64 + mi * 16 + (l & 15);
#pragma unroll
    for (int ks = 0; ks < 2; ++ks) {
      offA[mi][ks] = ra * 64 + ((((ks << 2) + (l >> 4)) ^ (ra & 7)) << 3);
      offB[mi][ks] = rb * 64 + ((((ks << 2) + (l >> 4)) ^ (rb & 7)) << 3);
    }
  }
  auto STAGE = [&](int kt, int bsel) {
    f16* la = sb + bsel * 16384;
    f16* lb = la + 8192;
    const char* as = Abyte + (long)kt * 128;
    const char* bs = Bbyte + (long)kt * 128;
#pragma unroll
    for (int i = 0; i < 4; ++i) gload16(as + offSrc[i], la + (i * 256 + (w << 6)) * 8);
#pragma unroll
    for (int i = 0; i < 4; ++i) gload16(bs + offSrc[i], lb + (i * 256 + (w << 6)) * 8);
  };
  f32x4 acc[4][4] = {};
  STAGE(0, 0);
  for (int kt = 0; kt < 64; ++kt) {
    const int cur = kt & 1;
    if (kt + 1 < 64) {
      STAGE(kt + 1, cur ^ 1);
      asm volatile("s_waitcnt vmcnt(8)" ::: "memory");
    } else {
      asm volatile("s_waitcnt vmcnt(0)" ::: "memory");
    }
    __builtin_amdgcn_s_barrier();
    asm volatile("" ::: "memory");
    const f16* la = sb + cur * 16384;
    const f16* lb = la + 8192;
#pragma unroll
    for (int ks = 0; ks < 2; ++ks) {
      const f16x8 invv = *(const f16x8*)(invl + kt * 64 + ks * 32 + ((l >> 4) << 3));
      f16x8 bf[4];
#pragma unroll
      for (int ni = 0; ni < 4; ++ni) bf[ni] = *(const f16x8*)(lb + offB[ni][ks]);
#pragma unroll
      for (int mi = 0; mi < 4; ++mi) {
        f16x8 af = *(const f16x8*)(la + offA[mi][ks]) * invv;  // A-side only: inv^2*4096
#pragma unroll
        for (int ni = 0; ni < 4; ++ni)
          acc[mi][ni] = __builtin_amdgcn_mfma_f32_16x16x32_f16(af, bf[ni], acc[mi][ni], 0, 0, 0);
      }
    }
    asm volatile("s_waitcnt lgkmcnt(0)" ::: "memory");
    __builtin_amdgcn_s_barrier();
    asm volatile("" ::: "memory");
  }
  const int gr0 = by * 128 + wr * 64 + (l >> 4) * 4;
  const int gc0 = bx * 128 + wc * 64 + (l & 15);
  float p = 0.f;
#pragma unroll
  for (int mi = 0; mi < 4; ++mi)
#pragma unroll
    for (int ni = 0; ni < 4; ++ni)
#pragma unroll
      for (int q = 0; q < 4; ++q) {
        float e = acc[mi][ni][q] * (1.0f / 4096.0f);
        if (gr0 + mi * 16 + q == gc0 + ni * 16) e -= 1.f;
        p += e * e;
      }
#pragma unroll
  for (int d = 32; d; d >>= 1) p += __shfl_down(p, d);
  __shared__ float red[4];
  if (l == 0) red[w] = p;
  __syncthreads();
  if (t == 0) parts[bid] = red[0] + red[1] + red[2] + red[3];
}

// ================= fused Q+K projection: one pass over Xk =====================================
// tile: 256 channels (full group) x 128 p; 512 threads (8 waves: 4 c-quads x 2 p-halves)
// Q[c,p] = sum_i Wq[c,i] X[i,p] + bq[c]  (natural [C][P]);  Kt[p,c] likewise transposed
__global__ void __launch_bounds__(512)
proj_qk(const float* __restrict__ X, const f16* __restrict__ Wq16, const f16* __restrict__ Wk16,
        const float* __restrict__ bq, const float* __restrict__ bk,
        f16* __restrict__ Q, f16* __restrict__ Kt) {
  __shared__ f16 sb[20480];  // Wq[8192] Wk[8192] Xt[4096]
  f16* Wqs = sb;
  f16* Wks = sb + 8192;
  f16* Xs = sb + 16384;
  const int t = threadIdx.x, l = t & 63, w = t >> 6;
  const int wrq = w >> 1, wcq = w & 1;  // c-quad (64), p-half (64)
  const int bg = blockIdx.z, g = bg & 3;
  const long b = bg >> 2;
  const int p0 = blockIdx.x * 128;
  const float* Xb = X + b * 1048576 + (long)g * 262144;  // [256 i][1024 p]
  const char* WqB = (const char*)(Wq16 + g * 65536);
  const char* WkB = (const char*)(Wk16 + g * 65536);
  int wOff[2];
#pragma unroll
  for (int i = 0; i < 2; ++i) {
    int c = i * 512 + t, row = c >> 2, slot = (c & 3) ^ ((row >> 1) & 3);
    wOff[i] = row * 512 + (slot << 4);  // row stride 256 f16 = 512 B
  }
  const int xp = t & 127, xc = t >> 7;
  const float* xS = Xb + (long)(xc * 8) * 1024 + p0 + xp;
  const int xo = swz(xp, xc);
  int offW[4], offX[4];
#pragma unroll
  for (int i = 0; i < 4; ++i) {
    int rc = wrq * 64 + i * 16 + (l & 15);
    offW[i] = swz(rc, l >> 4);
    int rp = wcq * 64 + i * 16 + (l & 15);
    offX[i] = swz(rp, l >> 4);
  }
  f32x4 accq[4][4] = {}, acck[4][4] = {};
  for (int k0 = 0; k0 < 256; k0 += 32) {
#pragma unroll
    for (int i = 0; i < 2; ++i) {
      gload16(WqB + wOff[i] + k0 * 2, Wqs + (i * 512 + (w << 6)) * 8);
      gload16(WkB + wOff[i] + k0 * 2, Wks + (i * 512 + (w << 6)) * 8);
    }
    const float* xs = xS + (long)k0 * 1024;
    f16x8 v;
#pragma unroll
    for (int d = 0; d < 8; ++d) v[d] = (f16)xs[(long)d * 1024];
    *(f16x8*)((char*)Xs + xo) = v;
    __syncthreads();
    f16x8 qf[4], kf[4], xf[4];
#pragma unroll
    for (int i = 0; i < 4; ++i) {
      qf[i] = *(const f16x8*)((const char*)Wqs + offW[i]);
      kf[i] = *(const f16x8*)((const char*)Wks + offW[i]);
      xf[i] = *(const f16x8*)((const char*)Xs + offX[i]);
    }
#pragma unroll
    for (int mi = 0; mi < 4; ++mi)
#pragma unroll
      for (int ni = 0; ni < 4; ++ni) {
        accq[mi][ni] = __builtin_amdgcn_mfma_f32_16x16x32_f16(qf[mi], xf[ni], accq[mi][ni], 0, 0, 0);
        acck[ni][mi] = __builtin_amdgcn_mfma_f32_16x16x32_f16(xf[ni], kf[mi], acck[ni][mi], 0, 0, 0);
      }
    __syncthreads();
  }
  // Q natural [C][P]
  f16* Qb = Q + b * 1048576 + (long)(g * 256 + wrq * 64) * 1024 + p0 + wcq * 64;
#pragma unroll
  for (int mi = 0; mi < 4; ++mi)
#pragma unroll
    for (int q = 0; q < 4; ++q) {
      float bv = bq[g * 256 + wrq * 64 + mi * 16 + (l >> 4) * 4 + q];
#pragma unroll
      for (int ni = 0; ni < 4; ++ni)
        Qb[(long)(mi * 16 + (l >> 4) * 4 + q) * 1024 + ni * 16 + (l & 15)] = (f16)(accq[mi][ni][q] + bv);
    }
  // Kt transposed [P][C]
  f16* Kb = Kt + b * 1048576 + (long)(p0 + wcq * 64) * 1024 + g * 256 + wrq * 64;
  float bcol[4];
#pragma unroll
  for (int ni = 0; ni < 4; ++ni) bcol[ni] = bk[g * 256 + wrq * 64 + ni * 16 + (l & 15)];
#pragma unroll
  for (int mi = 0; mi < 4; ++mi)
#pragma unroll
    for (int q = 0; q < 4; ++q)
#pragma unroll
      for (int ni = 0; ni < 4; ++ni)
        Kb[(long)(mi * 16 + (l >> 4) * 4 + q) * 1024 + ni * 16 + (l & 15)] = (f16)(acck[mi][ni][q] + bcol[ni]);
}

// ================= V projection: full-group tile, one pass over Xq ============================
// tile: 128 p x 256 channels; 512 threads; Vt[p,c] = sum_i X[i,p] Wv[c,i] + bv[c]
__global__ void __launch_bounds__(512)
proj_v(const float* __restrict__ X, const f16* __restrict__ Wv16, const float* __restrict__ bv,
       f16* __restrict__ Vt) {
  __shared__ f16 sb[12288];  // Wv[8192] Xt[4096]
  f16* Wvs = sb;
  f16* Xs = sb + 8192;
  const int t = threadIdx.x, l = t & 63, w = t >> 6;
  const int wrq = w >> 1, wcq = w & 1;  // c-quad, p-half
  const int bg = blockIdx.z, g = bg & 3;
  const long b = bg >> 2;
  const int p0 = blockIdx.x * 128;
  const float* Xb = X + b * 4194304 + (long)g * 1048576;  // [256 i][4096 p]
  const char* WvB = (const char*)(Wv16 + g * 65536);
  int wOff[2];
#pragma unroll
  for (int i = 0; i < 2; ++i) {
    int c = i * 512 + t, row = c >> 2, slot = (c & 3) ^ ((row >> 1) & 3);
    wOff[i] = row * 512 + (slot << 4);
  }
  const int xp = t & 127, xc = t >> 7;
  const float* xS = Xb + (long)(xc * 8) * 4096 + p0 + xp;
  const int xo = swz(xp, xc);
  int offW[4], offX[4];
#pragma unroll
  for (int i = 0; i < 4; ++i) {
    int rc = wrq * 64 + i * 16 + (l & 15);
    offW[i] = swz(rc, l >> 4);
    int rp = wcq * 64 + i * 16 + (l & 15);
    offX[i] = swz(rp, l >> 4);
  }
  f32x4 acc[4][4] = {};  // [p-frag][c-frag]
  for (int k0 = 0; k0 < 256; k0 += 32) {
#pragma unroll
    for (int i = 0; i < 2; ++i)
      gload16(WvB + wOff[i] + k0 * 2, Wvs + (i * 512 + (w << 6)) * 8);
    const float* xs = xS + (long)k0 * 4096;
    f16x8 v;
#pragma unroll
    for (int d = 0; d < 8; ++d) v[d] = (f16)xs[(long)d * 4096];
    *(f16x8*)((char*)Xs + xo) = v;
    __syncthreads();
    f16x8 wf[4], xf[4];
#pragma unroll
    for (int i = 0; i < 4; ++i) {
      wf[i] = *(const f16x8*)((const char*)Wvs + offW[i]);
      xf[i] = *(const f16x8*)((const char*)Xs + offX[i]);
    }
#pragma unroll
    for (int mi = 0; mi < 4; ++mi)
#pragma unroll
      for (int ni = 0; ni < 4; ++ni)
        acc[mi][ni] = __builtin_amdgcn_mfma_f32_16x16x32_f16(xf[mi], wf[ni], acc[mi][ni], 0, 0, 0);
    __syncthreads();
  }
  f16* Vb = Vt + b * 4194304 + (long)(p0 + wcq * 64) * 1024 + g * 256 + wrq * 64;
  float bcol[4];
#pragma unroll
  for (int ni = 0; ni < 4; ++ni) bcol[ni] = bv[g * 256 + wrq * 64 + ni * 16 + (l & 15)];
#pragma unroll
  for (int mi = 0; mi < 4; ++mi)
#pragma unroll
    for (int q = 0; q < 4; ++q)
#pragma unroll
      for (int ni = 0; ni < 4; ++ni)
        Vb[(long)(mi * 16 + (l >> 4) * 4 + q) * 1024 + ni * 16 + (l & 15)] = (f16)(acc[mi][ni][q] + bcol[ni]);
}

// ---------------- inv[b][j] = 1/colsum;  inv2s = inv^2*4096 (f16, for gram A-side scaling)
__global__ void __launch_bounds__(256)
inv_k(const float* __restrict__ colsum, float* __restrict__ inv, f16* __restrict__ inv2s) {
  int gid = blockIdx.x * 256 + threadIdx.x;  // 8*4096
  int b = gid >> 12, j = gid & 4095;
  const float* cp = colsum + (long)(b * 4) * 4096 + j;
  float s = 0.f;
#pragma unroll
  for (int my = 0; my < 4; ++my) s += cp[my * 4096];
  float iv = 1.f / s;
  inv[gid] = iv;
  inv2s[gid] = (f16)(iv * iv * 4096.0f);
}

// ---------------- streaming finalize: Hf f32 = E16*inv (f16x4 loads; scalar stores: Hf 4B-aligned)
__global__ void __launch_bounds__(256)
h_fin(const f16* __restrict__ E, float* __restrict__ Hf, const float* __restrict__ inv) {
  for (long g = blockIdx.x * 256L + threadIdx.x; g < 8388608L; g += (long)gridDim.x * 256) {
    long i4 = g * 4;
    int b = (int)(i4 >> 22), j = (int)(i4 & 4095);
    f16x4 e = *(const f16x4*)(E + i4);
    f32x4 iv = *(const f32x4*)(inv + (b << 12) + j);
    float* hp = Hf + i4;
    hp[0] = (float)e[0] * iv[0];
    hp[1] = (float)e[1] * iv[1];
    hp[2] = (float)e[2] * iv[2];
    hp[3] = (float)e[3] * iv[3];
  }
}

// ---------------- one fused f32->f16 weight convert (3 tensors of 262144)
__global__ void cvt3(const float* __restrict__ a, const float* __restrict__ b2,
                     const float* __restrict__ c, f16* __restrict__ da,
                     f16* __restrict__ db, f16* __restrict__ dc) {
  int i = blockIdx.x * 256 + threadIdx.x;
  int which = i >> 18, r = i & 262143;
  if (which == 0) da[r] = (f16)a[r];
  else if (which == 1) db[r] = (f16)b2[r];
  else dc[r] = (f16)c[r];
}

__global__ void __launch_bounds__(256)
finalize_k(const float* __restrict__ parts, float* __restrict__ o) {
  const int t = threadIdx.x;
  float s = 0.f;
  for (int i = t; i < 512; i += 256) s += parts[i];
#pragma unroll
  for (int d = 32; d; d >>= 1) s += __shfl_down(s, d);
  __shared__ float red[4];
  if ((t & 63) == 0) red[t >> 6] = s;
  __syncthreads();
  if (t == 0) *o = (red[0] + red[1] + red[2] + red[3]) * (1.0f / 8388608.0f);
}

extern "C" void kernel_launch(void* const* d_in, const int* in_sizes, int n_in,
                              void* d_out, int out_size, void* d_ws, size_t ws_size,
                              hipStream_t stream) {
  const float* Xq = (const float*)d_in[0];
  const float* Xk = (const float*)d_in[1];
  const float* Wq = (const float*)d_in[2];
  const float* bq = (const float*)d_in[3];
  const float* Wk = (const float*)d_in[4];
  const float* bk = (const float*)d_in[5];
  const float* Wv = (const float*)d_in[6];
  const float* bv = (const float*)d_in[7];
  float* out = (float*)d_out;
  float* loss_out = out + 33554432;
  float* Hf = out + 33554433;  // H f32 output [8][1024][4096]

  char* ws = (char*)d_ws;
  f16* W16q = (f16*)(ws);
  f16* W16k = (f16*)(ws + (1 << 19));
  f16* W16v = (f16*)(ws + 2L * (1 << 19));
  f16* Q16  = (f16*)(ws + 3L * (1 << 19));                                  // [8][1024][1024]
  f16* Kt16 = (f16*)(ws + 3L * (1 << 19) + (1L << 24));                     // [8][1024][1024]
  f16* Vt16 = (f16*)(ws + 3L * (1 << 19) + 2L * (1 << 24));                 // [8][4096][1024]
  f16* E16  = (f16*)(ws + 3L * (1 << 19) + 2L * (1 << 24) + (1L << 26));    // [8][1024][4096]
  f16* E16t = (f16*)(ws + 3L * (1 << 19) + 2L * (1 << 24) + 2L * (1 << 26));// [8][4096][1024]
  char* tail = ws + 3L * (1 << 19) + 2L * (1 << 24) + 3L * (1 << 26);
  float* parts = (float*)tail;                 // 512 f32
  float* invb  = (float*)(tail + 8192);        // [8][4096] f32
  f16*   inv2s = (f16*)(tail + 8192 + 131072); // [8][4096] f16
  // colsum [8][4][4096] f32 = 512KB, overlaps W16q (dead after projections)
  float* colsum = (float*)(ws);

  cvt3<<<3072, 256, 0, stream>>>(Wq, Wk, Wv, W16q, W16k, W16v);

  // Q [C x Pk] natural + K transposed [Pk x C] in one pass over Xk; V transposed [Pq x C]
  proj_qk<<<dim3(8, 1, 32), 512, 0, stream>>>(Xk, W16q, W16k, bq, bk, Q16, Kt16);
  proj_v <<<dim3(32, 1, 32), 512, 0, stream>>>(Xq, W16v, bv, Vt16);

  // E = exp(K^T V /32) -> E16 + E16t (f16) + column partial sums (256^2 tile, counted vmcnt)
  gemm256<2><<<512, 512, 0, stream>>>(Kt16, Vt16, nullptr, E16, E16t,
      1024, 1L << 20, 1L << 22, 0.03125f, colsum);

  inv_k<<<128, 256, 0, stream>>>(colsum, invb, inv2s);

  // out = Q * H = (Q * E^T) * inv[col]
  gemm256<3><<<512, 512, 0, stream>>>(Q16, E16t, out, nullptr, nullptr,
      1024, 1L << 20, 1L << 22, 1.0f, invb);

  // H f32 -> d_out (streaming, vectorized loads)
  h_fin<<<2048, 256, 0, stream>>>(E16, Hf, invb);

  // sparse loss: mean((H H^T - I)^2), H = E*inv fused via A-side inv^2 scaling
  gram_p<<<512, 256, 0, stream>>>(E16, inv2s, parts);
  finalize_k<<<1, 256, 0, stream>>>(parts, loss_out);
}

// Round 7
// 383.396 us; speedup vs baseline: 1.7090x; 1.0044x over previous
//
#include <hip/hip_runtime.h>

typedef _Float16 f16;
typedef f16 f16x4 __attribute__((ext_vector_type(4)));
typedef f16 f16x8 __attribute__((ext_vector_type(8)));
typedef float f32x4 __attribute__((ext_vector_type(4)));

// async global->LDS, 16B per lane; lds ptr must be wave-uniform base (HW adds lane*16)
__device__ __forceinline__ void gload16(const void* g, void* ldsbase) {
  __builtin_amdgcn_global_load_lds((const __attribute__((address_space(1))) unsigned int*)g,
                                   (__attribute__((address_space(3))) unsigned int*)ldsbase, 16, 0, 0);
}

// swizzled byte offset of 16B chunk c (k-chunk) of row `row` in a [rows][32] f16 tile (BK=32 kernels)
__device__ __forceinline__ int swz(int row, int c) {
  return row * 64 + ((c ^ ((row >> 1) & 3)) << 4);
}

// ================= 256x256 tile, BK=64, 512 threads, counted-vmcnt schedule =================
// NT GEMM: A [M x K], B [N x K] f16, K-contiguous. M=1024 (by: 4), N=4096 (bx: 16), batch 8.
// MODE 2: E = exp(A*B^T * scale) -> E16 [M x N] + E16t [N x M] + column partial sums (aux)
// MODE 3: C = (A*B^T) * aux[col]  (f32)
template<int MODE>
__global__ void __launch_bounds__(512, 2)
gemm256(const f16* __restrict__ A, const f16* __restrict__ Bm, float* __restrict__ Cf,
        f16* __restrict__ E16, f16* __restrict__ E16t,
        int K, long sA, long sB, float scale, float* __restrict__ aux) {
  __shared__ f16 sb[65536];  // 128 KB: A0[16384] B0[16384] A1[16384] B1[16384]
  const int t = threadIdx.x, l = t & 63, w = t >> 6;
  const int wr = w >> 2, wc = w & 3;
  const int bid = blockIdx.x;
  const int swzb = (bid & 7) * 64 + (bid >> 3);  // XCD-chunked (512 % 8 == 0)
  const long b = swzb >> 6;
  const int inner = swzb & 63;
  const int bx = inner >> 2, by = inner & 3;  // by fastest: 4 consecutive blocks share B-panel in L2
  const char* Abyte = (const char*)(A + b * sA + (long)(by * 256) * K);
  const char* Bbyte = (const char*)(Bm + b * sB + (long)(bx * 256) * K);

  // staging source byte-offsets (pre-swizzled source, linear LDS dest)
  int offSrc[4];
#pragma unroll
  for (int i = 0; i < 4; ++i) {
    int cid = i * 512 + t, row = cid >> 3, slot = cid & 7;
    offSrc[i] = row * (K * 2) + ((slot ^ (row & 7)) << 4);
  }
  // fragment element-offsets in the [256][64] swizzled tile
  int offAf[8][2], offBf[4][2];
#pragma unroll
  for (int mi = 0; mi < 8; ++mi) {
    int r = wr * 128 + mi * 16 + (l & 15);
#pragma unroll
    for (int ks = 0; ks < 2; ++ks)
      offAf[mi][ks] = r * 64 + ((((ks << 2) + (l >> 4)) ^ (r & 7)) << 3);
  }
#pragma unroll
  for (int ni = 0; ni < 4; ++ni) {
    int r = wc * 64 + ni * 16 + (l & 15);
#pragma unroll
    for (int ks = 0; ks < 2; ++ks)
      offBf[ni][ks] = r * 64 + ((((ks << 2) + (l >> 4)) ^ (r & 7)) << 3);
  }

  const int NT = K >> 6;
  f32x4 acc[8][4] = {};

  auto STAGE = [&](int kt, int bsel) {
    f16* la = sb + bsel * 32768;
    f16* lb = la + 16384;
    const char* as = Abyte + (long)kt * 128;
    const char* bs = Bbyte + (long)kt * 128;
#pragma unroll
    for (int i = 0; i < 4; ++i)
      gload16(as + offSrc[i], la + (i * 512 + (w << 6)) * 8);
#pragma unroll
    for (int i = 0; i < 4; ++i)
      gload16(bs + offSrc[i], lb + (i * 512 + (w << 6)) * 8);
  };

  STAGE(0, 0);
  for (int kt = 0; kt < NT; ++kt) {
    const int cur = kt & 1;
    if (kt + 1 < NT) {
      STAGE(kt + 1, cur ^ 1);
      asm volatile("s_waitcnt vmcnt(8)" ::: "memory");  // kt's 8 loads done; kt+1's 8 in flight
    } else {
      asm volatile("s_waitcnt vmcnt(0)" ::: "memory");
    }
    __builtin_amdgcn_s_barrier();
    asm volatile("" ::: "memory");
    const f16* la = sb + cur * 32768;
    const f16* lb = la + 16384;
#pragma unroll
    for (int ks = 0; ks < 2; ++ks) {
      f16x8 bf[4];
#pragma unroll
      for (int ni = 0; ni < 4; ++ni) bf[ni] = *(const f16x8*)(lb + offBf[ni][ks]);
#pragma unroll
      for (int mi = 0; mi < 8; ++mi) {
        f16x8 af = *(const f16x8*)(la + offAf[mi][ks]);
#pragma unroll
        for (int ni = 0; ni < 4; ++ni)
          acc[mi][ni] = __builtin_amdgcn_mfma_f32_16x16x32_f16(af, bf[ni], acc[mi][ni], 0, 0, 0);
      }
    }
    asm volatile("s_waitcnt lgkmcnt(0)" ::: "memory");
    __builtin_amdgcn_s_barrier();
    asm volatile("" ::: "memory");
  }

  const int i0 = by * 256, j0 = bx * 256;
  if (MODE == 2) {
    float csum[4] = {};
#pragma unroll
    for (int mi = 0; mi < 8; ++mi)
#pragma unroll
      for (int ni = 0; ni < 4; ++ni)
#pragma unroll
        for (int q = 0; q < 4; ++q) {
          float e = __expf(acc[mi][ni][q] * scale);
          acc[mi][ni][q] = e;
          csum[ni] += e;
        }
#pragma unroll
    for (int ni = 0; ni < 4; ++ni) {
      csum[ni] += __shfl_xor(csum[ni], 16);
      csum[ni] += __shfl_xor(csum[ni], 32);
    }
    float* colp = (float*)(sb + 34816);  // past the 64x264 slab region
    if (l < 16) {
#pragma unroll
      for (int ni = 0; ni < 4; ++ni) colp[wr * 256 + wc * 64 + ni * 16 + l] = csum[ni];
    }
    __syncthreads();
    if (t < 256) aux[(b * 4 + by) * 4096 + bx * 256 + t] = colp[t] + colp[256 + t];
    f16* E16b = E16 + b * 4194304L;
    f16* E16tb = E16t + b * 4194304L;
#pragma unroll
    for (int s = 0; s < 4; ++s) {
      if (wr == (s >> 1)) {  // slab s = rows [s*64, s*64+64) of the tile, padded stride 264
        const int h = s & 1;
#pragma unroll
        for (int m2 = 0; m2 < 4; ++m2)
#pragma unroll
          for (int ni = 0; ni < 4; ++ni)
#pragma unroll
            for (int q = 0; q < 4; ++q)
              sb[(m2 * 16 + (l >> 4) * 4 + q) * 264 + wc * 64 + ni * 16 + (l & 15)] =
                  (f16)acc[h * 4 + m2][ni][q];
      }
      __syncthreads();
#pragma unroll
      for (int ii = 0; ii < 4; ++ii) {  // E16 row-major readout, coalesced 16B
        int cid = ii * 512 + t, r = cid >> 5, cc = cid & 31;
        *(f16x8*)(E16b + (long)(i0 + s * 64 + r) * 4096 + j0 + cc * 8) =
            *(const f16x8*)(sb + r * 264 + cc * 8);
      }
      const int q4 = w >> 1, r8 = l >> 3, ic = l & 7;
#pragma unroll
      for (int ii = 0; ii < 4; ++ii) {  // E16t: column gather (bank-balanced), 16B stores
        int j = q4 * 64 + r8 * 8 + (w & 1) * 4 + ii;
        f16x8 v;
#pragma unroll
        for (int k2 = 0; k2 < 8; ++k2) v[k2] = sb[(ic * 8 + k2) * 264 + j];
        *(f16x8*)(E16tb + (long)(j0 + j) * 1024 + i0 + s * 64 + ic * 8) = v;
      }
      __syncthreads();
    }
  } else {  // MODE 3
    const float* ip = aux + b * 4096 + bx * 256 + wc * 64;
    float iv[4];
#pragma unroll
    for (int ni = 0; ni < 4; ++ni) iv[ni] = ip[ni * 16 + (l & 15)];
    float* Cb = Cf + b * 4194304L + (long)(by * 256 + wr * 128) * 4096 + bx * 256 + wc * 64;
#pragma unroll
    for (int mi = 0; mi < 8; ++mi)
#pragma unroll
      for (int ni = 0; ni < 4; ++ni)
#pragma unroll
        for (int q = 0; q < 4; ++q)
          Cb[(long)(mi * 16 + (l >> 4) * 4 + q) * 4096 + ni * 16 + (l & 15)] = acc[mi][ni][q] * iv[ni];
  }
}

// ================= Gram loss + fused Hf writer: 128x128 tile, BK=64, counted vmcnt ============
// mid[c,k]*4096 = sum_j (E[c,j]*inv2s[j]) * E[k,j],  inv2s = inv^2*4096 (A-side-only scaling)
// Block (b,by,bx) also writes Hf rows [128*by,+128), cols [512*bx,+512) = E*inv (f32) from its
// staged A-tiles during kt in [8bx, 8bx+8).  grid: 512 blocks, 256 threads, ~76KB -> 2 blocks/CU
__global__ void __launch_bounds__(256, 2)
gram_p(const f16* __restrict__ E, const f16* __restrict__ inv2sg,
       const float* __restrict__ invg, float* __restrict__ Hf, float* __restrict__ parts) {
  __shared__ f16 sb[37888];  // A0[8192] B0[8192] A1[8192] B1[8192] inv2s[4096] invf(512 f32)
  const int t = threadIdx.x, l = t & 63, w = t >> 6, wr = w >> 1, wc = w & 1;
  const int bid = blockIdx.x;
  const int swzb = (bid & 7) * 64 + (bid >> 3);  // XCD-chunked: each XCD owns one batch
  const long b = swzb >> 6;
  const int by = (swzb >> 3) & 7, bx = swzb & 7;
  const char* Abyte = (const char*)(E + b * 4194304L + (long)(by * 128) * 4096);
  const char* Bbyte = (const char*)(E + b * 4194304L + (long)(bx * 128) * 4096);
  f16* invl = sb + 32768;
  float* invf = (float*)(sb + 36864);
  {  // stage inv2s [4096] f16 = 8KB via 2 gload rounds (counts in prologue vmcnt)
    const char* ig = (const char*)(inv2sg + b * 4096);
    gload16(ig + (long)t * 16, invl + (w << 6) * 8);
    gload16(ig + 4096 + (long)t * 16, invl + 2048 + (w << 6) * 8);
  }
  {  // stage this block's 512 inv f32 (for Hf writing)
    float2 v = *(const float2*)(invg + b * 4096 + bx * 512 + 2 * t);
    invf[2 * t] = v.x;
    invf[2 * t + 1] = v.y;
  }
  asm volatile("s_waitcnt lgkmcnt(0)" ::: "memory");  // invf visible before first barrier
  int offSrc[4];
#pragma unroll
  for (int i = 0; i < 4; ++i) {
    int cid = i * 256 + t, row = cid >> 3, slot = cid & 7;
    offSrc[i] = row * 8192 + ((slot ^ (row & 7)) << 4);  // row stride = 4096 f16 = 8192 B
  }
  int offA[4][2], offB[4][2];
#pragma unroll
  for (int mi = 0; mi < 4; ++mi) {
    int ra = wr * 64 + mi * 16 + (l & 15);
    int rb = wc * 64 + mi * 16 + (l & 15);
#pragma unroll
    for (int ks = 0; ks < 2; ++ks) {
      offA[mi][ks] = ra * 64 + ((((ks << 2) + (l >> 4)) ^ (ra & 7)) << 3);
      offB[mi][ks] = rb * 64 + ((((ks << 2) + (l >> 4)) ^ (rb & 7)) << 3);
    }
  }
  auto STAGE = [&](int kt, int bsel) {
    f16* la = sb + bsel * 16384;
    f16* lb = la + 8192;
    const char* as = Abyte + (long)kt * 128;
    const char* bs = Bbyte + (long)kt * 128;
#pragma unroll
    for (int i = 0; i < 4; ++i) gload16(as + offSrc[i], la + (i * 256 + (w << 6)) * 8);
#pragma unroll
    for (int i = 0; i < 4; ++i) gload16(bs + offSrc[i], lb + (i * 256 + (w << 6)) * 8);
  };
  f32x4 acc[4][4] = {};
  STAGE(0, 0);
  for (int kt = 0; kt < 64; ++kt) {
    const int cur = kt & 1;
    if (kt + 1 < 64) {
      STAGE(kt + 1, cur ^ 1);
      asm volatile("s_waitcnt vmcnt(8)" ::: "memory");
    } else {
      asm volatile("s_waitcnt vmcnt(0)" ::: "memory");
    }
    __builtin_amdgcn_s_barrier();
    asm volatile("" ::: "memory");
    const f16* la = sb + cur * 16384;
    const f16* lb = la + 8192;
#pragma unroll
    for (int ks = 0; ks < 2; ++ks) {
      const f16x8 invv = *(const f16x8*)(invl + kt * 64 + ks * 32 + ((l >> 4) << 3));
      f16x8 bf[4];
#pragma unroll
      for (int ni = 0; ni < 4; ++ni) bf[ni] = *(const f16x8*)(lb + offB[ni][ks]);
#pragma unroll
      for (int mi = 0; mi < 4; ++mi) {
        f16x8 af = *(const f16x8*)(la + offA[mi][ks]) * invv;  // A-side only: inv^2*4096
#pragma unroll
        for (int ni = 0; ni < 4; ++ni)
          acc[mi][ni] = __builtin_amdgcn_mfma_f32_16x16x32_f16(af, bf[ni], acc[mi][ni], 0, 0, 0);
      }
    }
    if ((kt >> 3) == bx) {  // fused Hf writer: cols kt*64..+64 of this block's row-panel
      const float iv = invf[(kt & 7) * 64 + l];
      float* hp = Hf + b * 4194304L + (long)(by * 128) * 4096 + kt * 64 + l;
#pragma unroll
      for (int rr = 0; rr < 32; ++rr) {
        const int row = w + rr * 4;  // 4 waves x 32 rows
        f16 ev = la[row * 64 + ((((l >> 3) ^ (row & 7)) << 3) | (l & 7))];
        hp[(long)row * 4096] = (float)ev * iv;  // 64-lane coalesced scalar store
      }
    }
    asm volatile("s_waitcnt lgkmcnt(0)" ::: "memory");
    __builtin_amdgcn_s_barrier();
    asm volatile("" ::: "memory");
  }
  const int gr0 = by * 128 + wr * 64 + (l >> 4) * 4;
  const int gc0 = bx * 128 + wc * 64 + (l & 15);
  float p = 0.f;
#pragma unroll
  for (int mi = 0; mi < 4; ++mi)
#pragma unroll
    for (int ni = 0; ni < 4; ++ni)
#pragma unroll
      for (int q = 0; q < 4; ++q) {
        float e = acc[mi][ni][q] * (1.0f / 4096.0f);
        if (gr0 + mi * 16 + q == gc0 + ni * 16) e -= 1.f;
        p += e * e;
      }
#pragma unroll
  for (int d = 32; d; d >>= 1) p += __shfl_down(p, d);
  __shared__ float red[4];
  if (l == 0) red[w] = p;
  __syncthreads();
  if (t == 0) parts[bid] = red[0] + red[1] + red[2] + red[3];
}

// ================= fused Q+K projection: one pass over Xk =====================================
// tile: 256 channels (full group) x 128 p; 512 threads (8 waves: 4 c-quads x 2 p-halves)
// Q[c,p] = sum_i Wq[c,i] X[i,p] + bq[c]  (natural [C][P]);  Kt[p,c] likewise transposed
__global__ void __launch_bounds__(512)
proj_qk(const float* __restrict__ X, const f16* __restrict__ Wq16, const f16* __restrict__ Wk16,
        const float* __restrict__ bq, const float* __restrict__ bk,
        f16* __restrict__ Q, f16* __restrict__ Kt) {
  __shared__ f16 sb[20480];  // Wq[8192] Wk[8192] Xt[4096]
  f16* Wqs = sb;
  f16* Wks = sb + 8192;
  f16* Xs = sb + 16384;
  const int t = threadIdx.x, l = t & 63, w = t >> 6;
  const int wrq = w >> 1, wcq = w & 1;  // c-quad (64), p-half (64)
  const int bg = blockIdx.z, g = bg & 3;
  const long b = bg >> 2;
  const int p0 = blockIdx.x * 128;
  const float* Xb = X + b * 1048576 + (long)g * 262144;  // [256 i][1024 p]
  const char* WqB = (const char*)(Wq16 + g * 65536);
  const char* WkB = (const char*)(Wk16 + g * 65536);
  int wOff[2];
#pragma unroll
  for (int i = 0; i < 2; ++i) {
    int c = i * 512 + t, row = c >> 2, slot = (c & 3) ^ ((row >> 1) & 3);
    wOff[i] = row * 512 + (slot << 4);  // row stride 256 f16 = 512 B
  }
  const int xp = t & 127, xc = t >> 7;
  const float* xS = Xb + (long)(xc * 8) * 1024 + p0 + xp;
  const int xo = swz(xp, xc);
  int offW[4], offX[4];
#pragma unroll
  for (int i = 0; i < 4; ++i) {
    int rc = wrq * 64 + i * 16 + (l & 15);
    offW[i] = swz(rc, l >> 4);
    int rp = wcq * 64 + i * 16 + (l & 15);
    offX[i] = swz(rp, l >> 4);
  }
  f32x4 accq[4][4] = {}, acck[4][4] = {};
  for (int k0 = 0; k0 < 256; k0 += 32) {
#pragma unroll
    for (int i = 0; i < 2; ++i) {
      gload16(WqB + wOff[i] + k0 * 2, Wqs + (i * 512 + (w << 6)) * 8);
      gload16(WkB + wOff[i] + k0 * 2, Wks + (i * 512 + (w << 6)) * 8);
    }
    const float* xs = xS + (long)k0 * 1024;
    f16x8 v;
#pragma unroll
    for (int d = 0; d < 8; ++d) v[d] = (f16)xs[(long)d * 1024];
    *(f16x8*)((char*)Xs + xo) = v;
    __syncthreads();
    f16x8 qf[4], kf[4], xf[4];
#pragma unroll
    for (int i = 0; i < 4; ++i) {
      qf[i] = *(const f16x8*)((const char*)Wqs + offW[i]);
      kf[i] = *(const f16x8*)((const char*)Wks + offW[i]);
      xf[i] = *(const f16x8*)((const char*)Xs + offX[i]);
    }
#pragma unroll
    for (int mi = 0; mi < 4; ++mi)
#pragma unroll
      for (int ni = 0; ni < 4; ++ni) {
        accq[mi][ni] = __builtin_amdgcn_mfma_f32_16x16x32_f16(qf[mi], xf[ni], accq[mi][ni], 0, 0, 0);
        acck[ni][mi] = __builtin_amdgcn_mfma_f32_16x16x32_f16(xf[ni], kf[mi], acck[ni][mi], 0, 0, 0);
      }
    __syncthreads();
  }
  // Q natural [C][P]
  f16* Qb = Q + b * 1048576 + (long)(g * 256 + wrq * 64) * 1024 + p0 + wcq * 64;
#pragma unroll
  for (int mi = 0; mi < 4; ++mi)
#pragma unroll
    for (int q = 0; q < 4; ++q) {
      float bv = bq[g * 256 + wrq * 64 + mi * 16 + (l >> 4) * 4 + q];
#pragma unroll
      for (int ni = 0; ni < 4; ++ni)
        Qb[(long)(mi * 16 + (l >> 4) * 4 + q) * 1024 + ni * 16 + (l & 15)] = (f16)(accq[mi][ni][q] + bv);
    }
  // Kt transposed [P][C]
  f16* Kb = Kt + b * 1048576 + (long)(p0 + wcq * 64) * 1024 + g * 256 + wrq * 64;
  float bcol[4];
#pragma unroll
  for (int ni = 0; ni < 4; ++ni) bcol[ni] = bk[g * 256 + wrq * 64 + ni * 16 + (l & 15)];
#pragma unroll
  for (int mi = 0; mi < 4; ++mi)
#pragma unroll
    for (int q = 0; q < 4; ++q)
#pragma unroll
      for (int ni = 0; ni < 4; ++ni)
        Kb[(long)(mi * 16 + (l >> 4) * 4 + q) * 1024 + ni * 16 + (l & 15)] = (f16)(acck[mi][ni][q] + bcol[ni]);
}

// ================= V projection: full-group tile, one pass over Xq ============================
// tile: 128 p x 256 channels; 512 threads; Vt[p,c] = sum_i X[i,p] Wv[c,i] + bv[c]
__global__ void __launch_bounds__(512)
proj_v(const float* __restrict__ X, const f16* __restrict__ Wv16, const float* __restrict__ bv,
       f16* __restrict__ Vt) {
  __shared__ f16 sb[12288];  // Wv[8192] Xt[4096]
  f16* Wvs = sb;
  f16* Xs = sb + 8192;
  const int t = threadIdx.x, l = t & 63, w = t >> 6;
  const int wrq = w >> 1, wcq = w & 1;  // c-quad, p-half
  const int bg = blockIdx.z, g = bg & 3;
  const long b = bg >> 2;
  const int p0 = blockIdx.x * 128;
  const float* Xb = X + b * 4194304 + (long)g * 1048576;  // [256 i][4096 p]
  const char* WvB = (const char*)(Wv16 + g * 65536);
  int wOff[2];
#pragma unroll
  for (int i = 0; i < 2; ++i) {
    int c = i * 512 + t, row = c >> 2, slot = (c & 3) ^ ((row >> 1) & 3);
    wOff[i] = row * 512 + (slot << 4);
  }
  const int xp = t & 127, xc = t >> 7;
  const float* xS = Xb + (long)(xc * 8) * 4096 + p0 + xp;
  const int xo = swz(xp, xc);
  int offW[4], offX[4];
#pragma unroll
  for (int i = 0; i < 4; ++i) {
    int rc = wrq * 64 + i * 16 + (l & 15);
    offW[i] = swz(rc, l >> 4);
    int rp = wcq * 64 + i * 16 + (l & 15);
    offX[i] = swz(rp, l >> 4);
  }
  f32x4 acc[4][4] = {};  // [p-frag][c-frag]
  for (int k0 = 0; k0 < 256; k0 += 32) {
#pragma unroll
    for (int i = 0; i < 2; ++i)
      gload16(WvB + wOff[i] + k0 * 2, Wvs + (i * 512 + (w << 6)) * 8);
    const float* xs = xS + (long)k0 * 4096;
    f16x8 v;
#pragma unroll
    for (int d = 0; d < 8; ++d) v[d] = (f16)xs[(long)d * 4096];
    *(f16x8*)((char*)Xs + xo) = v;
    __syncthreads();
    f16x8 wf[4], xf[4];
#pragma unroll
    for (int i = 0; i < 4; ++i) {
      wf[i] = *(const f16x8*)((const char*)Wvs + offW[i]);
      xf[i] = *(const f16x8*)((const char*)Xs + offX[i]);
    }
#pragma unroll
    for (int mi = 0; mi < 4; ++mi)
#pragma unroll
      for (int ni = 0; ni < 4; ++ni)
        acc[mi][ni] = __builtin_amdgcn_mfma_f32_16x16x32_f16(xf[mi], wf[ni], acc[mi][ni], 0, 0, 0);
    __syncthreads();
  }
  f16* Vb = Vt + b * 4194304 + (long)(p0 + wcq * 64) * 1024 + g * 256 + wrq * 64;
  float bcol[4];
#pragma unroll
  for (int ni = 0; ni < 4; ++ni) bcol[ni] = bv[g * 256 + wrq * 64 + ni * 16 + (l & 15)];
#pragma unroll
  for (int mi = 0; mi < 4; ++mi)
#pragma unroll
    for (int q = 0; q < 4; ++q)
#pragma unroll
      for (int ni = 0; ni < 4; ++ni)
        Vb[(long)(mi * 16 + (l >> 4) * 4 + q) * 1024 + ni * 16 + (l & 15)] = (f16)(acc[mi][ni][q] + bcol[ni]);
}

// ---------------- inv[b][j] = 1/colsum;  inv2s = inv^2*4096 (f16, for gram A-side scaling)
__global__ void __launch_bounds__(256)
inv_k(const float* __restrict__ colsum, float* __restrict__ inv, f16* __restrict__ inv2s) {
  int gid = blockIdx.x * 256 + threadIdx.x;  // 8*4096
  int b = gid >> 12, j = gid & 4095;
  const float* cp = colsum + (long)(b * 4) * 4096 + j;
  float s = 0.f;
#pragma unroll
  for (int my = 0; my < 4; ++my) s += cp[my * 4096];
  float iv = 1.f / s;
  inv[gid] = iv;
  inv2s[gid] = (f16)(iv * iv * 4096.0f);
}

// ---------------- one fused f32->f16 weight convert (3 tensors of 262144)
__global__ void cvt3(const float* __restrict__ a, const float* __restrict__ b2,
                     const float* __restrict__ c, f16* __restrict__ da,
                     f16* __restrict__ db, f16* __restrict__ dc) {
  int i = blockIdx.x * 256 + threadIdx.x;
  int which = i >> 18, r = i & 262143;
  if (which == 0) da[r] = (f16)a[r];
  else if (which == 1) db[r] = (f16)b2[r];
  else dc[r] = (f16)c[r];
}

__global__ void __launch_bounds__(256)
finalize_k(const float* __restrict__ parts, float* __restrict__ o) {
  const int t = threadIdx.x;
  float s = 0.f;
  for (int i = t; i < 512; i += 256) s += parts[i];
#pragma unroll
  for (int d = 32; d; d >>= 1) s += __shfl_down(s, d);
  __shared__ float red[4];
  if ((t & 63) == 0) red[t >> 6] = s;
  __syncthreads();
  if (t == 0) *o = (red[0] + red[1] + red[2] + red[3]) * (1.0f / 8388608.0f);
}

extern "C" void kernel_launch(void* const* d_in, const int* in_sizes, int n_in,
                              void* d_out, int out_size, void* d_ws, size_t ws_size,
                              hipStream_t stream) {
  const float* Xq = (const float*)d_in[0];
  const float* Xk = (const float*)d_in[1];
  const float* Wq = (const float*)d_in[2];
  const float* bq = (const float*)d_in[3];
  const float* Wk = (const float*)d_in[4];
  const float* bk = (const float*)d_in[5];
  const float* Wv = (const float*)d_in[6];
  const float* bv = (const float*)d_in[7];
  float* out = (float*)d_out;
  float* loss_out = out + 33554432;
  float* Hf = out + 33554433;  // H f32 output [8][1024][4096]

  char* ws = (char*)d_ws;
  f16* W16q = (f16*)(ws);
  f16* W16k = (f16*)(ws + (1 << 19));
  f16* W16v = (f16*)(ws + 2L * (1 << 19));
  f16* Q16  = (f16*)(ws + 3L * (1 << 19));                                  // [8][1024][1024]
  f16* Kt16 = (f16*)(ws + 3L * (1 << 19) + (1L << 24));                     // [8][1024][1024]
  f16* Vt16 = (f16*)(ws + 3L * (1 << 19) + 2L * (1 << 24));                 // [8][4096][1024]
  f16* E16  = (f16*)(ws + 3L * (1 << 19) + 2L * (1 << 24) + (1L << 26));    // [8][1024][4096]
  f16* E16t = (f16*)(ws + 3L * (1 << 19) + 2L * (1 << 24) + 2L * (1 << 26));// [8][4096][1024]
  char* tail = ws + 3L * (1 << 19) + 2L * (1 << 24) + 3L * (1 << 26);
  float* parts = (float*)tail;                 // 512 f32
  float* invb  = (float*)(tail + 8192);        // [8][4096] f32
  f16*   inv2s = (f16*)(tail + 8192 + 131072); // [8][4096] f16
  // colsum [8][4][4096] f32 = 512KB, overlaps W16q (dead after projections)
  float* colsum = (float*)(ws);

  cvt3<<<3072, 256, 0, stream>>>(Wq, Wk, Wv, W16q, W16k, W16v);

  // Q [C x Pk] natural + K transposed [Pk x C] in one pass over Xk; V transposed [Pq x C]
  proj_qk<<<dim3(8, 1, 32), 512, 0, stream>>>(Xk, W16q, W16k, bq, bk, Q16, Kt16);
  proj_v <<<dim3(32, 1, 32), 512, 0, stream>>>(Xq, W16v, bv, Vt16);

  // E = exp(K^T V /32) -> E16 + E16t (f16) + column partial sums (256^2 tile, counted vmcnt)
  gemm256<2><<<512, 512, 0, stream>>>(Kt16, Vt16, nullptr, E16, E16t,
      1024, 1L << 20, 1L << 22, 0.03125f, colsum);

  inv_k<<<128, 256, 0, stream>>>(colsum, invb, inv2s);

  // out = Q * H = (Q * E^T) * inv[col]
  gemm256<3><<<512, 512, 0, stream>>>(Q16, E16t, out, nullptr, nullptr,
      1024, 1L << 20, 1L << 22, 1.0f, invb);

  // sparse loss: mean((H H^T - I)^2) with fused Hf = E*inv writer (replaces h_fin)
  gram_p<<<512, 256, 0, stream>>>(E16, inv2s, invb, Hf, parts);
  finalize_k<<<1, 256, 0, stream>>>(parts, loss_out);
}